// Round 7
// baseline (388.542 us; speedup 1.0000x reference)
//
#include <hip/hip_runtime.h>

// ---------------------------------------------------------------------------
// GAT pipeline. N=30000, E=600000, IN=128, H=8, HD=32, OUT=256.
// R1: removed per-node scalar atomic (925->549us).
// R2: bf16 MFMA GEMMs + bf16 gather (549->414us).
// R3: agg edge-loop software-pipelined x4.
// R4: pool 512 blocks; agg unroll x8 (390->360us).
// R5/R6: GEMM+softmax and GEMM+LN fused (360->334us). pexp precompute was
//     neutral for agg (memory-path bound) -> reverted in R7.
// R7: dense kernels re-tiled 32rows x 256cols BK=32 (938 blocks, ~21KB LDS,
//     ~15 waves/CU; the 64-row tiles ran at 1.8 blocks/CU = latency-bound
//     streaming). alpha fused into gemm_xp epilogue. zero merged into repack.
//     13 -> 11 dispatches.
// ---------------------------------------------------------------------------

typedef __attribute__((ext_vector_type(8))) short bf16x8;   // 8 bf16 (4 VGPRs)
typedef __attribute__((ext_vector_type(4))) float f32x4;    // MFMA acc

__device__ __forceinline__ float leaky_f(float v, float s) { return v > 0.f ? v : s * v; }
__device__ __forceinline__ unsigned short f2bf(float f) {   // RNE, no NaN expected
  unsigned int u = __float_as_uint(f);
  u += 0x7fffu + ((u >> 16) & 1u);
  return (unsigned short)(u >> 16);
}
__device__ __forceinline__ float bf2f(unsigned short u) {
  return __uint_as_float(((unsigned int)u) << 16);
}
__device__ __forceinline__ float red16_sum(float v) {
#pragma unroll
  for (int m = 1; m < 16; m <<= 1) v += __shfl_xor(v, m);
  return v;
}
__device__ __forceinline__ float red16_max(float v) {
#pragma unroll
  for (int m = 1; m < 16; m <<= 1) v = fmaxf(v, __shfl_xor(v, m));
  return v;
}

// ---- repack weights + zero accumulators (merged; independent jobs)
__global__ void repack_zero_kernel(const float* __restrict__ W, const float* __restrict__ fc_w,
                                   const float* __restrict__ gfc_w,
                                   unsigned short* __restrict__ Wb,
                                   unsigned short* __restrict__ fcB, float* __restrict__ gfcT,
                                   int* __restrict__ deg, float* __restrict__ xg,
                                   float* __restrict__ S, int n) {
  int i = blockIdx.x * 256 + threadIdx.x;
  if (i < 256 * 128) {
    int c = i >> 7, k = i & 127;
    Wb[i] = f2bf(W[((c >> 5) * 128 + k) * 32 + (c & 31)]);
  } else if (i < 256 * 128 + 256 * 256) {
    int j = i - 256 * 128;
    fcB[j] = f2bf(fc_w[j]);
  } else if (i < 256 * 128 + 2 * 256 * 256) {
    int j = i - 256 * 128 - 256 * 256;
    gfcT[j] = gfc_w[(j & 255) * 256 + (j >> 8)];
  }
  if (i < n) deg[i] = 0;
  if (i < 256) xg[i] = 0.f;
  if (i == 0) S[0] = 0.f;
}

// ---- shared 32x256 GEMM body. Block = 32 rows x 256 cols, 4 waves
// (wave w -> cols w*64..w*64+63). BK=32; A slice + B slice restaged per k0.
// LDS stride 36 shorts (=18 dwords) -> <=2-way bank aliasing (free).
template <int A_BF16>
__device__ __forceinline__ void gemm_body_32x256(
    const void* __restrict__ Av, const unsigned short* __restrict__ B,
    int row0, int n_rows, int K, short As[32][36], short Bs[256][36],
    f32x4 acc[2][4]) {
  int t = threadIdx.x;
  int wave = t >> 6, lane = t & 63;
  int m16 = lane & 15, quad = lane >> 4;
  int wc = wave * 64;
  for (int k0 = 0; k0 < K; k0 += 32) {
    // stage A slice: 32 rows x 32 k
    {
      int row = t >> 3, k = (t & 7) * 4;
      int ar = row0 + row; if (ar > n_rows - 1) ar = n_rows - 1;
      if (A_BF16) {
        const unsigned short* A = (const unsigned short*)Av;
        uint2 q = *(const uint2*)(A + (size_t)ar * K + k0 + k);
        *(uint2*)&As[row][k] = q;
      } else {
        const float* A = (const float*)Av;
        float4 q = *(const float4*)(A + (size_t)ar * K + k0 + k);
        unsigned int lo = (unsigned int)f2bf(q.x) | ((unsigned int)f2bf(q.y) << 16);
        unsigned int hi = (unsigned int)f2bf(q.z) | ((unsigned int)f2bf(q.w) << 16);
        *(uint2*)&As[row][k] = make_uint2(lo, hi);
      }
    }
    // stage B slice: 256 n x 32 k
#pragma unroll
    for (int p = 0; p < 4; ++p) {
      int e = (p * 256 + t) * 8;
      int nn = e >> 5, k = e & 31;
      uint4 q = *(const uint4*)(B + (size_t)nn * K + k0 + k);
      *(uint4*)&Bs[nn][k] = q;
    }
    __syncthreads();
    bf16x8 af[2], bfr[4];
#pragma unroll
    for (int i = 0; i < 2; ++i)
      af[i] = *(const bf16x8*)&As[i * 16 + m16][quad * 8];
#pragma unroll
    for (int j = 0; j < 4; ++j)
      bfr[j] = *(const bf16x8*)&Bs[wc + j * 16 + m16][quad * 8];
#pragma unroll
    for (int i = 0; i < 2; ++i)
#pragma unroll
      for (int j = 0; j < 4; ++j)
        acc[i][j] = __builtin_amdgcn_mfma_f32_16x16x32_bf16(af[i], bfr[j], acc[i][j], 0, 0, 0);
    __syncthreads();
  }
}

// ---- GEMM0 fused with alpha: xp = x@W (bf16 out); asrc/adst = per-head dots
// computed from fp32 accumulators (wave w owns heads 2w, 2w+1 exclusively).
__global__ __launch_bounds__(256) void gemm_xp(
    const float* __restrict__ A, const unsigned short* __restrict__ B,
    const float* __restrict__ a_src, const float* __restrict__ a_dst,
    unsigned short* __restrict__ xpb, float* __restrict__ asrc,
    float* __restrict__ adst, int n_rows) {
  __shared__ short As[32][36];
  __shared__ short Bs[256][36];
  int t = threadIdx.x;
  int wave = t >> 6, lane = t & 63;
  int m16 = lane & 15, quad = lane >> 4;
  int wc = wave * 64;
  int row0 = blockIdx.x * 32;
  f32x4 acc[2][4];
#pragma unroll
  for (int i = 0; i < 2; ++i)
#pragma unroll
    for (int j = 0; j < 4; ++j) acc[i][j] = (f32x4){0.f, 0.f, 0.f, 0.f};
  gemm_body_32x256<0>(A, B, row0, n_rows, 128, As, Bs, acc);

  float av[4], bd[4];
#pragma unroll
  for (int j = 0; j < 4; ++j) {
    int c = wc + j * 16 + m16;
    av[j] = a_src[c];
    bd[j] = a_dst[c];
  }
#pragma unroll
  for (int i = 0; i < 2; ++i)
#pragma unroll
    for (int v = 0; v < 4; ++v) {
      int r = row0 + i * 16 + quad * 4 + v;
      if (r < n_rows) {
#pragma unroll
        for (int j = 0; j < 4; ++j)
          xpb[(size_t)r * 256 + wc + j * 16 + m16] = f2bf(acc[i][j][v]);
      }
      // per-head dots: 16-lane groups span exactly one head per j-pair
      float s0 = acc[i][0][v] * av[0] + acc[i][1][v] * av[1];
      float s1 = acc[i][2][v] * av[2] + acc[i][3][v] * av[3];
      float d0 = acc[i][0][v] * bd[0] + acc[i][1][v] * bd[1];
      float d1 = acc[i][2][v] * bd[2] + acc[i][3][v] * bd[3];
      s0 = red16_sum(s0); s1 = red16_sum(s1);
      d0 = red16_sum(d0); d1 = red16_sum(d1);
      if (m16 == 0 && r < n_rows) {
        asrc[(size_t)r * 8 + 2 * wave] = s0;
        asrc[(size_t)r * 8 + 2 * wave + 1] = s1;
        adst[(size_t)r * 8 + 2 * wave] = d0;
        adst[(size_t)r * 8 + 2 * wave + 1] = d1;
      }
    }
}

// ---- GEMM1 fused with row softmax: z1 = leaky(xloc@fc^T+b, 0.01);
// sa = softmax(z1); x2b = bf16(leaky(xloc*sa, 0.2)).
__global__ __launch_bounds__(256) void gemm_sm(
    const float* __restrict__ A, const unsigned short* __restrict__ B,
    const float* __restrict__ bias, unsigned short* __restrict__ x2b, int n_rows) {
  __shared__ short As[32][36];
  __shared__ short Bs[256][36];
  __shared__ float red[4][32];
  __shared__ float rowv[32];
  int t = threadIdx.x;
  int wave = t >> 6, lane = t & 63;
  int m16 = lane & 15, quad = lane >> 4;
  int wc = wave * 64;
  int row0 = blockIdx.x * 32;
  f32x4 acc[2][4];
#pragma unroll
  for (int i = 0; i < 2; ++i)
#pragma unroll
    for (int j = 0; j < 4; ++j) acc[i][j] = (f32x4){0.f, 0.f, 0.f, 0.f};
  gemm_body_32x256<0>(A, B, row0, n_rows, 256, As, Bs, acc);

  float bvv[4];
#pragma unroll
  for (int j = 0; j < 4; ++j) bvv[j] = bias[wc + j * 16 + m16];
#pragma unroll
  for (int i = 0; i < 2; ++i)
#pragma unroll
    for (int j = 0; j < 4; ++j)
#pragma unroll
      for (int v = 0; v < 4; ++v)
        acc[i][j][v] = leaky_f(acc[i][j][v] + bvv[j], 0.01f);

  // row max
  float M[2][4];
#pragma unroll
  for (int i = 0; i < 2; ++i)
#pragma unroll
    for (int v = 0; v < 4; ++v) {
      float m = fmaxf(fmaxf(acc[i][0][v], acc[i][1][v]), fmaxf(acc[i][2][v], acc[i][3][v]));
      M[i][v] = red16_max(m);
    }
  if (m16 == 0)
#pragma unroll
    for (int i = 0; i < 2; ++i)
#pragma unroll
      for (int v = 0; v < 4; ++v) red[wave][i * 16 + quad * 4 + v] = M[i][v];
  __syncthreads();
  if (t < 32) rowv[t] = fmaxf(fmaxf(red[0][t], red[1][t]), fmaxf(red[2][t], red[3][t]));
  __syncthreads();
#pragma unroll
  for (int i = 0; i < 2; ++i)
#pragma unroll
    for (int v = 0; v < 4; ++v) M[i][v] = rowv[i * 16 + quad * 4 + v];
  __syncthreads();

  // exp + row sum
  float S[2][4];
#pragma unroll
  for (int i = 0; i < 2; ++i)
#pragma unroll
    for (int v = 0; v < 4; ++v) {
#pragma unroll
      for (int j = 0; j < 4; ++j) acc[i][j][v] = __expf(acc[i][j][v] - M[i][v]);
      float s = acc[i][0][v] + acc[i][1][v] + acc[i][2][v] + acc[i][3][v];
      S[i][v] = red16_sum(s);
    }
  if (m16 == 0)
#pragma unroll
    for (int i = 0; i < 2; ++i)
#pragma unroll
      for (int v = 0; v < 4; ++v) red[wave][i * 16 + quad * 4 + v] = S[i][v];
  __syncthreads();
  if (t < 32) rowv[t] = red[0][t] + red[1][t] + red[2][t] + red[3][t];
  __syncthreads();

  // x2 = leaky(xloc * e * inv, 0.2) -> bf16
#pragma unroll
  for (int i = 0; i < 2; ++i)
#pragma unroll
    for (int v = 0; v < 4; ++v) {
      int r = row0 + i * 16 + quad * 4 + v;
      float inv = 1.f / rowv[i * 16 + quad * 4 + v];
      if (r < n_rows) {
#pragma unroll
        for (int j = 0; j < 4; ++j) {
          int c = wc + j * 16 + m16;
          float xv = A[(size_t)r * 256 + c];
          x2b[(size_t)r * 256 + c] = f2bf(leaky_f(xv * acc[i][j][v] * inv, 0.2f));
        }
      }
    }
}

// ---- GEMM2 fused with LayerNorm + L2 norm + gate.
__global__ __launch_bounds__(256) void gemm_ln(
    const unsigned short* __restrict__ A, const unsigned short* __restrict__ B,
    const float* __restrict__ bias, const float* __restrict__ ln_w,
    const float* __restrict__ ln_b, const float* __restrict__ gate_w,
    const float* __restrict__ gate_b, float* __restrict__ Cout,
    float* __restrict__ egate, int n_rows) {
  __shared__ short As[32][36];
  __shared__ short Bs[256][36];
  __shared__ float red[4][32];
  __shared__ float rowv[32];
  int t = threadIdx.x;
  int wave = t >> 6, lane = t & 63;
  int m16 = lane & 15, quad = lane >> 4;
  int wc = wave * 64;
  int row0 = blockIdx.x * 32;
  f32x4 acc[2][4];
#pragma unroll
  for (int i = 0; i < 2; ++i)
#pragma unroll
    for (int j = 0; j < 4; ++j) acc[i][j] = (f32x4){0.f, 0.f, 0.f, 0.f};
  gemm_body_32x256<1>(A, B, row0, n_rows, 256, As, Bs, acc);

  float bvv[4], lw[4], lb[4], gw[4];
#pragma unroll
  for (int j = 0; j < 4; ++j) {
    int c = wc + j * 16 + m16;
    bvv[j] = bias[c]; lw[j] = ln_w[c]; lb[j] = ln_b[c]; gw[j] = gate_w[c];
  }
#pragma unroll
  for (int i = 0; i < 2; ++i)
#pragma unroll
    for (int j = 0; j < 4; ++j)
#pragma unroll
      for (int v = 0; v < 4; ++v) acc[i][j][v] += bvv[j];

  // round 1: mean
  float MU[2][4];
#pragma unroll
  for (int i = 0; i < 2; ++i)
#pragma unroll
    for (int v = 0; v < 4; ++v)
      MU[i][v] = red16_sum(acc[i][0][v] + acc[i][1][v] + acc[i][2][v] + acc[i][3][v]);
  if (m16 == 0)
#pragma unroll
    for (int i = 0; i < 2; ++i)
#pragma unroll
      for (int v = 0; v < 4; ++v) red[wave][i * 16 + quad * 4 + v] = MU[i][v];
  __syncthreads();
  if (t < 32) rowv[t] = (red[0][t] + red[1][t] + red[2][t] + red[3][t]) * (1.f / 256.f);
  __syncthreads();
#pragma unroll
  for (int i = 0; i < 2; ++i)
#pragma unroll
    for (int v = 0; v < 4; ++v) MU[i][v] = rowv[i * 16 + quad * 4 + v];
  __syncthreads();
#pragma unroll
  for (int i = 0; i < 2; ++i)
#pragma unroll
    for (int j = 0; j < 4; ++j)
#pragma unroll
      for (int v = 0; v < 4; ++v) acc[i][j][v] -= MU[i][v];

  // round 2: variance -> rstd
  float RS[2][4];
#pragma unroll
  for (int i = 0; i < 2; ++i)
#pragma unroll
    for (int v = 0; v < 4; ++v) {
      float q = acc[i][0][v] * acc[i][0][v] + acc[i][1][v] * acc[i][1][v] +
                acc[i][2][v] * acc[i][2][v] + acc[i][3][v] * acc[i][3][v];
      RS[i][v] = red16_sum(q);
    }
  if (m16 == 0)
#pragma unroll
    for (int i = 0; i < 2; ++i)
#pragma unroll
      for (int v = 0; v < 4; ++v) red[wave][i * 16 + quad * 4 + v] = RS[i][v];
  __syncthreads();
  if (t < 32)
    rowv[t] = rsqrtf((red[0][t] + red[1][t] + red[2][t] + red[3][t]) * (1.f / 256.f) + 1e-5f);
  __syncthreads();
#pragma unroll
  for (int i = 0; i < 2; ++i)
#pragma unroll
    for (int v = 0; v < 4; ++v) RS[i][v] = rowv[i * 16 + quad * 4 + v];
  __syncthreads();
#pragma unroll
  for (int i = 0; i < 2; ++i)
#pragma unroll
    for (int j = 0; j < 4; ++j)
#pragma unroll
      for (int v = 0; v < 4; ++v)
        acc[i][j][v] = acc[i][j][v] * RS[i][v] * lw[j] + lb[j];

  // round 3: L2 norm
  float NV[2][4];
#pragma unroll
  for (int i = 0; i < 2; ++i)
#pragma unroll
    for (int v = 0; v < 4; ++v) {
      float q = acc[i][0][v] * acc[i][0][v] + acc[i][1][v] * acc[i][1][v] +
                acc[i][2][v] * acc[i][2][v] + acc[i][3][v] * acc[i][3][v];
      NV[i][v] = red16_sum(q);
    }
  if (m16 == 0)
#pragma unroll
    for (int i = 0; i < 2; ++i)
#pragma unroll
      for (int v = 0; v < 4; ++v) red[wave][i * 16 + quad * 4 + v] = NV[i][v];
  __syncthreads();
  if (t < 32)
    rowv[t] = 1.f / fmaxf(sqrtf(red[0][t] + red[1][t] + red[2][t] + red[3][t]), 1e-12f);
  __syncthreads();
#pragma unroll
  for (int i = 0; i < 2; ++i)
#pragma unroll
    for (int v = 0; v < 4; ++v) NV[i][v] = rowv[i * 16 + quad * 4 + v];
  __syncthreads();
#pragma unroll
  for (int i = 0; i < 2; ++i)
#pragma unroll
    for (int j = 0; j < 4; ++j)
#pragma unroll
      for (int v = 0; v < 4; ++v) acc[i][j][v] *= NV[i][v];

  // round 4: gate logit -> egate
  float GP[2][4];
#pragma unroll
  for (int i = 0; i < 2; ++i)
#pragma unroll
    for (int v = 0; v < 4; ++v) {
      float g = acc[i][0][v] * gw[0] + acc[i][1][v] * gw[1] +
                acc[i][2][v] * gw[2] + acc[i][3][v] * gw[3];
      GP[i][v] = red16_sum(g);
    }
  if (m16 == 0)
#pragma unroll
    for (int i = 0; i < 2; ++i)
#pragma unroll
      for (int v = 0; v < 4; ++v) red[wave][i * 16 + quad * 4 + v] = GP[i][v];
  __syncthreads();
  if (t < 32 && row0 + t < n_rows) {
    float gp = red[0][t] + red[1][t] + red[2][t] + red[3][t];
    egate[row0 + t] = __expf(gp + gate_b[0]);  // |gp| <= ~0.8, safe
  }
  // store y
#pragma unroll
  for (int i = 0; i < 2; ++i)
#pragma unroll
    for (int v = 0; v < 4; ++v) {
      int r = row0 + i * 16 + quad * 4 + v;
      if (r < n_rows) {
#pragma unroll
        for (int j = 0; j < 4; ++j)
          Cout[(size_t)r * 256 + wc + j * 16 + m16] = acc[i][j][v];
      }
    }
}

// ---- CSR build
__global__ void hist_kernel(const int* __restrict__ dst, int* __restrict__ deg, int e) {
  int i = blockIdx.x * 256 + threadIdx.x;
  if (i < e) atomicAdd(&deg[dst[i]], 1);
}

__global__ __launch_bounds__(1024) void scan_kernel(const int* __restrict__ deg,
                                                    int* __restrict__ offsets,
                                                    int* __restrict__ curs, int n) {
  __shared__ int wsum[16];
  __shared__ int carry_s;
  int t = threadIdx.x, lane = t & 63, wv = t >> 6;
  if (t == 0) { carry_s = 0; offsets[0] = 0; }
  __syncthreads();
  for (int base = 0; base < n; base += 4096) {
    int i0 = base + t * 4;
    int4 v = make_int4(0, 0, 0, 0);
    if (i0 + 3 < n) v = *(const int4*)(deg + i0);
    else {
      if (i0 < n) v.x = deg[i0];
      if (i0 + 1 < n) v.y = deg[i0 + 1];
      if (i0 + 2 < n) v.z = deg[i0 + 2];
    }
    int p1 = v.x, p2 = p1 + v.y, p3 = p2 + v.z, p4 = p3 + v.w;
    int s = p4;
#pragma unroll
    for (int d = 1; d < 64; d <<= 1) {
      int u = __shfl_up(s, d);
      if (lane >= d) s += u;
    }
    if (lane == 63) wsum[wv] = s;
    __syncthreads();
    int woff = 0, total = 0;
#pragma unroll
    for (int k = 0; k < 16; ++k) {
      int wsk = wsum[k];
      woff += (k < wv) ? wsk : 0;
      total += wsk;
    }
    int carry = carry_s;
    int excl = carry + woff + s - p4;
    if (i0 < n)     { offsets[i0 + 1] = excl + p1; curs[i0]     = excl; }
    if (i0 + 1 < n) { offsets[i0 + 2] = excl + p2; curs[i0 + 1] = excl + p1; }
    if (i0 + 2 < n) { offsets[i0 + 3] = excl + p3; curs[i0 + 2] = excl + p2; }
    if (i0 + 3 < n) { offsets[i0 + 4] = excl + p4; curs[i0 + 3] = excl + p3; }
    __syncthreads();
    if (t == 0) carry_s = carry + total;
    __syncthreads();
  }
}

// ---- simple scatter (pexp precompute reverted: agg is memory-path bound,
// in-loop exp is free under it — measured R5 vs R6 both 48.8us)
__global__ void scatter_kernel(const int* __restrict__ src, const int* __restrict__ dst,
                               int* __restrict__ cursor, int* __restrict__ ssrc, int e) {
  int i = blockIdx.x * 256 + threadIdx.x;
  if (i < e) {
    int p = atomicAdd(&cursor[dst[i]], 1);
    ssrc[p] = src[i];
  }
}

// ---- edge aggregation, bf16 gather, fp32 accumulate, unroll x8/x4/scalar.
__global__ __launch_bounds__(256) void agg_kernel(
    const unsigned short* __restrict__ xpb, const float* __restrict__ asrc,
    const float* __restrict__ adst, const int* __restrict__ offsets,
    const int* __restrict__ ssrc, const float4* __restrict__ conv_b4,
    float4* __restrict__ xloc4, int n_nodes) {
  int lane = threadIdx.x & 63, w = threadIdx.x >> 6;
  int n = blockIdx.x * 4 + w;
  if (n >= n_nodes) return;
  int h = lane >> 3;
  float ad = adst[n * 8 + h];
  float p = __expf(leaky_f(asrc[n * 8 + h] + ad, 0.2f));
  ushort4 xq = ((const ushort4*)(xpb + (size_t)n * 256))[lane];
  float4 acc;
  acc.x = p * bf2f(xq.x); acc.y = p * bf2f(xq.y);
  acc.z = p * bf2f(xq.z); acc.w = p * bf2f(xq.w);
  float ssum = p;
  int beg = offsets[n], end = offsets[n + 1];
  int j = beg;
  for (; j + 8 <= end; j += 8) {
    int sv[8];
#pragma unroll
    for (int u = 0; u < 8; ++u) sv[u] = ssrc[j + u];
    float a[8];
#pragma unroll
    for (int u = 0; u < 8; ++u) a[u] = asrc[sv[u] * 8 + h];
    ushort4 q[8];
#pragma unroll
    for (int u = 0; u < 8; ++u) q[u] = ((const ushort4*)(xpb + (size_t)sv[u] * 256))[lane];
#pragma unroll
    for (int u = 0; u < 8; ++u) {
      float pu = __expf(leaky_f(a[u] + ad, 0.2f));
      acc.x += pu * bf2f(q[u].x); acc.y += pu * bf2f(q[u].y);
      acc.z += pu * bf2f(q[u].z); acc.w += pu * bf2f(q[u].w);
      ssum += pu;
    }
  }
  for (; j + 4 <= end; j += 4) {
    int sv0 = ssrc[j], sv1 = ssrc[j + 1], sv2 = ssrc[j + 2], sv3 = ssrc[j + 3];
    float a0 = asrc[sv0 * 8 + h];
    float a1 = asrc[sv1 * 8 + h];
    float a2 = asrc[sv2 * 8 + h];
    float a3 = asrc[sv3 * 8 + h];
    ushort4 q0 = ((const ushort4*)(xpb + (size_t)sv0 * 256))[lane];
    ushort4 q1 = ((const ushort4*)(xpb + (size_t)sv1 * 256))[lane];
    ushort4 q2 = ((const ushort4*)(xpb + (size_t)sv2 * 256))[lane];
    ushort4 q3 = ((const ushort4*)(xpb + (size_t)sv3 * 256))[lane];
    float p0 = __expf(leaky_f(a0 + ad, 0.2f));
    float p1 = __expf(leaky_f(a1 + ad, 0.2f));
    float p2 = __expf(leaky_f(a2 + ad, 0.2f));
    float p3 = __expf(leaky_f(a3 + ad, 0.2f));
    acc.x += p0 * bf2f(q0.x); acc.y += p0 * bf2f(q0.y);
    acc.z += p0 * bf2f(q0.z); acc.w += p0 * bf2f(q0.w);
    acc.x += p1 * bf2f(q1.x); acc.y += p1 * bf2f(q1.y);
    acc.z += p1 * bf2f(q1.z); acc.w += p1 * bf2f(q1.w);
    acc.x += p2 * bf2f(q2.x); acc.y += p2 * bf2f(q2.y);
    acc.z += p2 * bf2f(q2.z); acc.w += p2 * bf2f(q2.w);
    acc.x += p3 * bf2f(q3.x); acc.y += p3 * bf2f(q3.y);
    acc.z += p3 * bf2f(q3.z); acc.w += p3 * bf2f(q3.w);
    ssum += p0 + p1 + p2 + p3;
  }
  for (; j < end; ++j) {
    int sv = ssrc[j];
    float a1 = asrc[sv * 8 + h];
    ushort4 q = ((const ushort4*)(xpb + (size_t)sv * 256))[lane];
    float p1 = __expf(leaky_f(a1 + ad, 0.2f));
    acc.x += p1 * bf2f(q.x); acc.y += p1 * bf2f(q.y);
    acc.z += p1 * bf2f(q.z); acc.w += p1 * bf2f(q.w);
    ssum += p1;
  }
  float inv = 1.f / (ssum + 1e-16f);
  float4 b = conv_b4[lane];
  float4 o;
  o.x = acc.x * inv + b.x; o.y = acc.y * inv + b.y;
  o.z = acc.z * inv + b.z; o.w = acc.w * inv + b.w;
  xloc4[(size_t)n * 64 + lane] = o;
}

// ---- pooling + Ssum: per-block partials, one atomic per block (512 blocks)
__global__ __launch_bounds__(256) void pool_kernel(const float* __restrict__ xloc,
                                                   const float* __restrict__ egate,
                                                   float* __restrict__ xg,
                                                   float* __restrict__ Ssum, int n) {
  int c = threadIdx.x;
  int rpb = (n + (int)gridDim.x - 1) / (int)gridDim.x;
  int r0 = blockIdx.x * rpb;
  int r1 = r0 + rpb; if (r1 > n) r1 = n;
  float acc = 0.f, gs = 0.f;
  for (int r = r0; r < r1; ++r) {
    float g = egate[r];
    acc += g * xloc[(size_t)r * 256 + c];
    gs += g;
  }
  atomicAdd(&xg[c], acc);
  if (c == 0) atomicAdd(Ssum, gs);
}

__global__ __launch_bounds__(256) void gfc_kernel(const float* __restrict__ xg,
                                                  const float* __restrict__ S,
                                                  const float* __restrict__ gfcT,
                                                  const float* __restrict__ gfc_b,
                                                  float* __restrict__ ga) {
  __shared__ float xs[256];
  __shared__ float red[256];
  int t = threadIdx.x;
  float invS = 1.f / (S[0] + 1e-16f);
  xs[t] = xg[t] * invS;
  __syncthreads();
  float acc = gfc_b[t];
  for (int i = 0; i < 256; ++i) acc += xs[i] * gfcT[i * 256 + t];
  acc = fmaxf(acc, 0.f);
  red[t] = acc;
  __syncthreads();
  for (int s = 128; s > 0; s >>= 1) {
    if (t < s) red[t] = fmaxf(red[t], red[t + s]);
    __syncthreads();
  }
  float m = red[0];
  __syncthreads();
  float e = __expf(acc - m);
  red[t] = e;
  __syncthreads();
  for (int s = 128; s > 0; s >>= 1) {
    if (t < s) red[t] += red[t + s];
    __syncthreads();
  }
  ga[t] = e / red[0];
}

__global__ void out_kernel(const float4* __restrict__ xloc4, const float4* __restrict__ ga4,
                           float4* __restrict__ out4, int total4) {
  int i = blockIdx.x * 256 + threadIdx.x;
  if (i >= total4) return;
  float4 v = xloc4[i];
  float4 g = ga4[i & 63];
  v.x *= g.x; v.y *= g.y; v.z *= g.z; v.w *= g.w;
  out4[i] = v;
}

extern "C" void kernel_launch(void* const* d_in, const int* in_sizes, int n_in,
                              void* d_out, int out_size, void* d_ws, size_t ws_size,
                              hipStream_t stream) {
  const float* x      = (const float*)d_in[0];
  const int* edge_idx = (const int*)d_in[1];
  const float* W      = (const float*)d_in[4];
  const float* a_src  = (const float*)d_in[5];
  const float* a_dst  = (const float*)d_in[6];
  const float* conv_b = (const float*)d_in[7];
  const float* fc_w   = (const float*)d_in[8];
  const float* fc_b   = (const float*)d_in[9];
  const float* ln_w   = (const float*)d_in[10];
  const float* ln_b   = (const float*)d_in[11];
  const float* gate_w = (const float*)d_in[12];
  const float* gate_b = (const float*)d_in[13];
  const float* gfc_w  = (const float*)d_in[14];
  const float* gfc_b  = (const float*)d_in[15];
  (void)n_in; (void)out_size; (void)ws_size;

  int N = in_sizes[0] / 128;
  int E = in_sizes[1] / 2;
  const int* src = edge_idx;
  const int* dst = edge_idx + E;

  char* p = (char*)d_ws;
  auto alloc = [&](size_t bytes) -> char* {
    char* r = p;
    p += (bytes + 255) & ~(size_t)255;
    return r;
  };
  float*          xloc = (float*)alloc((size_t)N * 256 * 4);          // conv out / final x
  unsigned short* xpb  = (unsigned short*)alloc((size_t)N * 256 * 2); // bf16 xp
  unsigned short* x2b  = (unsigned short*)alloc((size_t)N * 256 * 2); // bf16 x2
  float* asrc  = (float*)alloc((size_t)N * 8 * 4);
  float* adst  = (float*)alloc((size_t)N * 8 * 4);
  unsigned short* Wb   = (unsigned short*)alloc(256 * 128 * 2);
  unsigned short* fcB  = (unsigned short*)alloc(256 * 256 * 2);
  float* gfcT  = (float*)alloc(256 * 256 * 4);
  float* egate = (float*)alloc((size_t)N * 4);
  int*   deg   = (int*)alloc((size_t)N * 4);
  int*   offs  = (int*)alloc((size_t)(N + 1) * 4);
  int*   curs  = (int*)alloc((size_t)N * 4);
  int*   ssrc  = (int*)alloc((size_t)E * 4);
  float* Ssum  = (float*)alloc(256);
  float* xg    = (float*)alloc(1024);
  float* ga    = (float*)alloc(1024);

  int eb = (E + 255) / 256;
  int g32 = (N + 31) / 32;

  repack_zero_kernel<<<(256 * 128 + 2 * 256 * 256 + 255) / 256, 256, 0, stream>>>(
      W, fc_w, gfc_w, Wb, fcB, gfcT, deg, xg, Ssum, N);
  // xp(bf16) = x @ W, alpha fused
  gemm_xp<<<g32, 256, 0, stream>>>(x, Wb, a_src, a_dst, xpb, asrc, adst, N);
  hist_kernel<<<eb, 256, 0, stream>>>(dst, deg, E);
  scan_kernel<<<1, 1024, 0, stream>>>(deg, offs, curs, N);
  scatter_kernel<<<eb, 256, 0, stream>>>(src, dst, curs, ssrc, E);
  agg_kernel<<<(N + 3) / 4, 256, 0, stream>>>(
      xpb, asrc, adst, offs, ssrc, (const float4*)conv_b, (float4*)xloc, N);
  // fused: z1 -> softmax -> x2(bf16)
  gemm_sm<<<g32, 256, 0, stream>>>(xloc, fcB, fc_b, x2b, N);
  // fused: x3 -> LN -> L2 -> gate; writes xloc + egate
  gemm_ln<<<g32, 256, 0, stream>>>(x2b, fcB, fc_b, ln_w, ln_b, gate_w, gate_b,
                                   xloc, egate, N);
  pool_kernel<<<512, 256, 0, stream>>>(xloc, egate, xg, Ssum, N);
  gfc_kernel<<<1, 256, 0, stream>>>(xg, Ssum, gfcT, gfc_b, ga);
  out_kernel<<<(N * 64 + 255) / 256, 256, 0, stream>>>(
      (const float4*)xloc, (const float4*)ga, (float4*)d_out, N * 64);
}

// Round 8
// 359.543 us; speedup vs baseline: 1.0807x; 1.0807x over previous
//
#include <hip/hip_runtime.h>

// ---------------------------------------------------------------------------
// GAT pipeline. N=30000, E=600000, IN=128, H=8, HD=32, OUT=256.
// R1: removed per-node scalar atomic (925->549us).
// R2: bf16 MFMA GEMMs + bf16 gather (549->414us).
// R3/R4: agg software-pipelined x8; pool 512 blocks (->360us).
// R5/R6: GEMM+softmax, GEMM+LN fusion (->334us).
// R7 FAILED: 32-row/BK=32 re-tile regressed to 388us (8 MFMA/barrier vs
//     ~600cy staging latency; all pipes idle; LDS stride 36 = conflicting).
// R8: revert to 64x256/BK=64 (stride 72 = free 2-way); add REGISTER PREFETCH
//     (load k0+64 slices into VGPRs after the post-store barrier -> global
//     latency overlaps the 32-MFMA block). Keep alpha fusion + zero merge.
// ---------------------------------------------------------------------------

typedef __attribute__((ext_vector_type(8))) short bf16x8;   // 8 bf16 (4 VGPRs)
typedef __attribute__((ext_vector_type(4))) float f32x4;    // MFMA acc

__device__ __forceinline__ float leaky_f(float v, float s) { return v > 0.f ? v : s * v; }
__device__ __forceinline__ unsigned short f2bf(float f) {   // RNE, no NaN expected
  unsigned int u = __float_as_uint(f);
  u += 0x7fffu + ((u >> 16) & 1u);
  return (unsigned short)(u >> 16);
}
__device__ __forceinline__ float bf2f(unsigned short u) {
  return __uint_as_float(((unsigned int)u) << 16);
}
__device__ __forceinline__ float red16_sum(float v) {
#pragma unroll
  for (int m = 1; m < 16; m <<= 1) v += __shfl_xor(v, m);
  return v;
}
__device__ __forceinline__ float red16_max(float v) {
#pragma unroll
  for (int m = 1; m < 16; m <<= 1) v = fmaxf(v, __shfl_xor(v, m));
  return v;
}

// ---- repack weights + zero accumulators (merged; independent jobs)
__global__ void repack_zero_kernel(const float* __restrict__ W, const float* __restrict__ fc_w,
                                   const float* __restrict__ gfc_w,
                                   unsigned short* __restrict__ Wb,
                                   unsigned short* __restrict__ fcB, float* __restrict__ gfcT,
                                   int* __restrict__ deg, float* __restrict__ xg,
                                   float* __restrict__ S, int n) {
  int i = blockIdx.x * 256 + threadIdx.x;
  if (i < 256 * 128) {
    int c = i >> 7, k = i & 127;
    Wb[i] = f2bf(W[((c >> 5) * 128 + k) * 32 + (c & 31)]);
  } else if (i < 256 * 128 + 256 * 256) {
    int j = i - 256 * 128;
    fcB[j] = f2bf(fc_w[j]);
  } else if (i < 256 * 128 + 2 * 256 * 256) {
    int j = i - 256 * 128 - 256 * 256;
    gfcT[j] = gfc_w[(j & 255) * 256 + (j >> 8)];
  }
  if (i < n) deg[i] = 0;
  if (i < 256) xg[i] = 0.f;
  if (i == 0) S[0] = 0.f;
}

// ---- shared 64x256 GEMM body with register prefetch. Block = 64 rows x
// 256 cols, 4 waves (wave w -> cols w*64..w*64+63, all 64 rows). BK=64.
// LDS stride 72 shorts = 144B -> 4-bank offset -> 2-way aliasing (free).
template <int A_BF16>
__device__ __forceinline__ void gemm_body_64x256_pf(
    const void* __restrict__ Av, const unsigned short* __restrict__ B,
    int row0, int n_rows, int K, short As[64][72], short Bs[256][72],
    f32x4 acc[4][4]) {
  int t = threadIdx.x;
  int wave = t >> 6, lane = t & 63;
  int m16 = lane & 15, quad = lane >> 4;
  int wc = wave * 64;

  float4 pa[4];   // fp32-A prefetch regs
  uint4 pab[2];   // bf16-A prefetch regs
  uint4 pb[8];    // B prefetch regs

  auto loadA = [&](int k0) {
    if (A_BF16) {
      const unsigned short* A = (const unsigned short*)Av;
#pragma unroll
      for (int p = 0; p < 2; ++p) {
        int e = (p * 256 + t) * 8;
        int ar = row0 + (e >> 6); if (ar > n_rows - 1) ar = n_rows - 1;
        pab[p] = *(const uint4*)(A + (size_t)ar * K + k0 + (e & 63));
      }
    } else {
      const float* A = (const float*)Av;
#pragma unroll
      for (int p = 0; p < 4; ++p) {
        int e = (p * 256 + t) * 4;
        int ar = row0 + (e >> 6); if (ar > n_rows - 1) ar = n_rows - 1;
        pa[p] = *(const float4*)(A + (size_t)ar * K + k0 + (e & 63));
      }
    }
  };
  auto loadB = [&](int k0) {
#pragma unroll
    for (int p = 0; p < 8; ++p) {
      int e = (p * 256 + t) * 8;
      pb[p] = *(const uint4*)(B + (size_t)(e >> 6) * K + k0 + (e & 63));
    }
  };

  loadA(0);
  loadB(0);
  for (int k0 = 0; k0 < K; k0 += 64) {
    // drain prefetch regs into LDS
    if (A_BF16) {
#pragma unroll
      for (int p = 0; p < 2; ++p) {
        int e = (p * 256 + t) * 8;
        *(uint4*)&As[e >> 6][e & 63] = pab[p];
      }
    } else {
#pragma unroll
      for (int p = 0; p < 4; ++p) {
        int e = (p * 256 + t) * 4;
        unsigned int lo = (unsigned int)f2bf(pa[p].x) | ((unsigned int)f2bf(pa[p].y) << 16);
        unsigned int hi = (unsigned int)f2bf(pa[p].z) | ((unsigned int)f2bf(pa[p].w) << 16);
        *(uint2*)&As[e >> 6][e & 63] = make_uint2(lo, hi);
      }
    }
#pragma unroll
    for (int p = 0; p < 8; ++p) {
      int e = (p * 256 + t) * 8;
      *(uint4*)&Bs[e >> 6][e & 63] = pb[p];
    }
    __syncthreads();
    // issue next slice's loads NOW; latency overlaps the MFMA block below
    if (k0 + 64 < K) { loadA(k0 + 64); loadB(k0 + 64); }
#pragma unroll
    for (int ks = 0; ks < 64; ks += 32) {
      bf16x8 af[4], bfr[4];
#pragma unroll
      for (int i = 0; i < 4; ++i)
        af[i] = *(const bf16x8*)&As[i * 16 + m16][ks + quad * 8];
#pragma unroll
      for (int j = 0; j < 4; ++j)
        bfr[j] = *(const bf16x8*)&Bs[wc + j * 16 + m16][ks + quad * 8];
#pragma unroll
      for (int i = 0; i < 4; ++i)
#pragma unroll
        for (int j = 0; j < 4; ++j)
          acc[i][j] = __builtin_amdgcn_mfma_f32_16x16x32_bf16(af[i], bfr[j], acc[i][j], 0, 0, 0);
    }
    __syncthreads();
  }
}

// ---- GEMM0 fused with alpha: xp = x@W (bf16 out); asrc/adst per-head dots
// from fp32 accumulators (wave w owns heads 2w, 2w+1: cols wc..wc+31, +32..63).
__global__ __launch_bounds__(256) void gemm_xp(
    const float* __restrict__ A, const unsigned short* __restrict__ B,
    const float* __restrict__ a_src, const float* __restrict__ a_dst,
    unsigned short* __restrict__ xpb, float* __restrict__ asrc,
    float* __restrict__ adst, int n_rows) {
  __shared__ short As[64][72];
  __shared__ short Bs[256][72];
  int t = threadIdx.x;
  int wave = t >> 6, lane = t & 63;
  int m16 = lane & 15, quad = lane >> 4;
  int wc = wave * 64;
  int row0 = blockIdx.x * 64;
  f32x4 acc[4][4];
#pragma unroll
  for (int i = 0; i < 4; ++i)
#pragma unroll
    for (int j = 0; j < 4; ++j) acc[i][j] = (f32x4){0.f, 0.f, 0.f, 0.f};
  gemm_body_64x256_pf<0>(A, B, row0, n_rows, 128, As, Bs, acc);

  float av[4], bd[4];
#pragma unroll
  for (int j = 0; j < 4; ++j) {
    int c = wc + j * 16 + m16;
    av[j] = a_src[c];
    bd[j] = a_dst[c];
  }
#pragma unroll
  for (int i = 0; i < 4; ++i)
#pragma unroll
    for (int v = 0; v < 4; ++v) {
      int r = row0 + i * 16 + quad * 4 + v;
      if (r < n_rows) {
#pragma unroll
        for (int j = 0; j < 4; ++j)
          xpb[(size_t)r * 256 + wc + j * 16 + m16] = f2bf(acc[i][j][v]);
      }
      float s0 = acc[i][0][v] * av[0] + acc[i][1][v] * av[1];
      float s1 = acc[i][2][v] * av[2] + acc[i][3][v] * av[3];
      float d0 = acc[i][0][v] * bd[0] + acc[i][1][v] * bd[1];
      float d1 = acc[i][2][v] * bd[2] + acc[i][3][v] * bd[3];
      s0 = red16_sum(s0); s1 = red16_sum(s1);
      d0 = red16_sum(d0); d1 = red16_sum(d1);
      if (m16 == 0 && r < n_rows) {
        asrc[(size_t)r * 8 + 2 * wave] = s0;
        asrc[(size_t)r * 8 + 2 * wave + 1] = s1;
        adst[(size_t)r * 8 + 2 * wave] = d0;
        adst[(size_t)r * 8 + 2 * wave + 1] = d1;
      }
    }
}

// ---- GEMM1 fused with row softmax: z1 = leaky(xloc@fc^T+b, 0.01);
// sa = softmax(z1); x2b = bf16(leaky(xloc*sa, 0.2)).
__global__ __launch_bounds__(256) void gemm_sm(
    const float* __restrict__ A, const unsigned short* __restrict__ B,
    const float* __restrict__ bias, unsigned short* __restrict__ x2b, int n_rows) {
  __shared__ short As[64][72];
  __shared__ short Bs[256][72];
  __shared__ float red[4][64];
  __shared__ float rowv[64];
  int t = threadIdx.x;
  int wave = t >> 6, lane = t & 63;
  int m16 = lane & 15, quad = lane >> 4;
  int wc = wave * 64;
  int row0 = blockIdx.x * 64;
  f32x4 acc[4][4];
#pragma unroll
  for (int i = 0; i < 4; ++i)
#pragma unroll
    for (int j = 0; j < 4; ++j) acc[i][j] = (f32x4){0.f, 0.f, 0.f, 0.f};
  gemm_body_64x256_pf<0>(A, B, row0, n_rows, 256, As, Bs, acc);

  float bvv[4];
#pragma unroll
  for (int j = 0; j < 4; ++j) bvv[j] = bias[wc + j * 16 + m16];
#pragma unroll
  for (int i = 0; i < 4; ++i)
#pragma unroll
    for (int j = 0; j < 4; ++j)
#pragma unroll
      for (int v = 0; v < 4; ++v)
        acc[i][j][v] = leaky_f(acc[i][j][v] + bvv[j], 0.01f);

  // row max
  float M[4][4];
#pragma unroll
  for (int i = 0; i < 4; ++i)
#pragma unroll
    for (int v = 0; v < 4; ++v) {
      float m = fmaxf(fmaxf(acc[i][0][v], acc[i][1][v]), fmaxf(acc[i][2][v], acc[i][3][v]));
      M[i][v] = red16_max(m);
    }
  if (m16 == 0)
#pragma unroll
    for (int i = 0; i < 4; ++i)
#pragma unroll
      for (int v = 0; v < 4; ++v) red[wave][i * 16 + quad * 4 + v] = M[i][v];
  __syncthreads();
  if (t < 64) rowv[t] = fmaxf(fmaxf(red[0][t], red[1][t]), fmaxf(red[2][t], red[3][t]));
  __syncthreads();
#pragma unroll
  for (int i = 0; i < 4; ++i)
#pragma unroll
    for (int v = 0; v < 4; ++v) M[i][v] = rowv[i * 16 + quad * 4 + v];
  __syncthreads();

  // exp + row sum
  float S[4][4];
#pragma unroll
  for (int i = 0; i < 4; ++i)
#pragma unroll
    for (int v = 0; v < 4; ++v) {
#pragma unroll
      for (int j = 0; j < 4; ++j) acc[i][j][v] = __expf(acc[i][j][v] - M[i][v]);
      float s = acc[i][0][v] + acc[i][1][v] + acc[i][2][v] + acc[i][3][v];
      S[i][v] = red16_sum(s);
    }
  if (m16 == 0)
#pragma unroll
    for (int i = 0; i < 4; ++i)
#pragma unroll
      for (int v = 0; v < 4; ++v) red[wave][i * 16 + quad * 4 + v] = S[i][v];
  __syncthreads();
  if (t < 64) rowv[t] = red[0][t] + red[1][t] + red[2][t] + red[3][t];
  __syncthreads();

  // x2 = leaky(xloc * e * inv, 0.2) -> bf16
#pragma unroll
  for (int i = 0; i < 4; ++i)
#pragma unroll
    for (int v = 0; v < 4; ++v) {
      int r = row0 + i * 16 + quad * 4 + v;
      float inv = 1.f / rowv[i * 16 + quad * 4 + v];
      if (r < n_rows) {
#pragma unroll
        for (int j = 0; j < 4; ++j) {
          int c = wc + j * 16 + m16;
          float xv = A[(size_t)r * 256 + c];
          x2b[(size_t)r * 256 + c] = f2bf(leaky_f(xv * acc[i][j][v] * inv, 0.2f));
        }
      }
    }
}

// ---- GEMM2 fused with LayerNorm + L2 norm + gate.
__global__ __launch_bounds__(256) void gemm_ln(
    const unsigned short* __restrict__ A, const unsigned short* __restrict__ B,
    const float* __restrict__ bias, const float* __restrict__ ln_w,
    const float* __restrict__ ln_b, const float* __restrict__ gate_w,
    const float* __restrict__ gate_b, float* __restrict__ Cout,
    float* __restrict__ egate, int n_rows) {
  __shared__ short As[64][72];
  __shared__ short Bs[256][72];
  __shared__ float red[4][64];
  __shared__ float rowv[64];
  int t = threadIdx.x;
  int wave = t >> 6, lane = t & 63;
  int m16 = lane & 15, quad = lane >> 4;
  int wc = wave * 64;
  int row0 = blockIdx.x * 64;
  f32x4 acc[4][4];
#pragma unroll
  for (int i = 0; i < 4; ++i)
#pragma unroll
    for (int j = 0; j < 4; ++j) acc[i][j] = (f32x4){0.f, 0.f, 0.f, 0.f};
  gemm_body_64x256_pf<1>(A, B, row0, n_rows, 256, As, Bs, acc);

  float bvv[4], lw[4], lb[4], gw[4];
#pragma unroll
  for (int j = 0; j < 4; ++j) {
    int c = wc + j * 16 + m16;
    bvv[j] = bias[c]; lw[j] = ln_w[c]; lb[j] = ln_b[c]; gw[j] = gate_w[c];
  }
#pragma unroll
  for (int i = 0; i < 4; ++i)
#pragma unroll
    for (int j = 0; j < 4; ++j)
#pragma unroll
      for (int v = 0; v < 4; ++v) acc[i][j][v] += bvv[j];

  // round 1: mean
  float MU[4][4];
#pragma unroll
  for (int i = 0; i < 4; ++i)
#pragma unroll
    for (int v = 0; v < 4; ++v)
      MU[i][v] = red16_sum(acc[i][0][v] + acc[i][1][v] + acc[i][2][v] + acc[i][3][v]);
  if (m16 == 0)
#pragma unroll
    for (int i = 0; i < 4; ++i)
#pragma unroll
      for (int v = 0; v < 4; ++v) red[wave][i * 16 + quad * 4 + v] = MU[i][v];
  __syncthreads();
  if (t < 64) rowv[t] = (red[0][t] + red[1][t] + red[2][t] + red[3][t]) * (1.f / 256.f);
  __syncthreads();
#pragma unroll
  for (int i = 0; i < 4; ++i)
#pragma unroll
    for (int v = 0; v < 4; ++v) MU[i][v] = rowv[i * 16 + quad * 4 + v];
  __syncthreads();
#pragma unroll
  for (int i = 0; i < 4; ++i)
#pragma unroll
    for (int j = 0; j < 4; ++j)
#pragma unroll
      for (int v = 0; v < 4; ++v) acc[i][j][v] -= MU[i][v];

  // round 2: variance -> rstd
  float RS[4][4];
#pragma unroll
  for (int i = 0; i < 4; ++i)
#pragma unroll
    for (int v = 0; v < 4; ++v) {
      float q = acc[i][0][v] * acc[i][0][v] + acc[i][1][v] * acc[i][1][v] +
                acc[i][2][v] * acc[i][2][v] + acc[i][3][v] * acc[i][3][v];
      RS[i][v] = red16_sum(q);
    }
  if (m16 == 0)
#pragma unroll
    for (int i = 0; i < 4; ++i)
#pragma unroll
      for (int v = 0; v < 4; ++v) red[wave][i * 16 + quad * 4 + v] = RS[i][v];
  __syncthreads();
  if (t < 64)
    rowv[t] = rsqrtf((red[0][t] + red[1][t] + red[2][t] + red[3][t]) * (1.f / 256.f) + 1e-5f);
  __syncthreads();
#pragma unroll
  for (int i = 0; i < 4; ++i)
#pragma unroll
    for (int v = 0; v < 4; ++v) RS[i][v] = rowv[i * 16 + quad * 4 + v];
  __syncthreads();
#pragma unroll
  for (int i = 0; i < 4; ++i)
#pragma unroll
    for (int j = 0; j < 4; ++j)
#pragma unroll
      for (int v = 0; v < 4; ++v)
        acc[i][j][v] = acc[i][j][v] * RS[i][v] * lw[j] + lb[j];

  // round 3: L2 norm
  float NV[4][4];
#pragma unroll
  for (int i = 0; i < 4; ++i)
#pragma unroll
    for (int v = 0; v < 4; ++v) {
      float q = acc[i][0][v] * acc[i][0][v] + acc[i][1][v] * acc[i][1][v] +
                acc[i][2][v] * acc[i][2][v] + acc[i][3][v] * acc[i][3][v];
      NV[i][v] = red16_sum(q);
    }
  if (m16 == 0)
#pragma unroll
    for (int i = 0; i < 4; ++i)
#pragma unroll
      for (int v = 0; v < 4; ++v) red[wave][i * 16 + quad * 4 + v] = NV[i][v];
  __syncthreads();
  if (t < 64)
    rowv[t] = 1.f / fmaxf(sqrtf(red[0][t] + red[1][t] + red[2][t] + red[3][t]), 1e-12f);
  __syncthreads();
#pragma unroll
  for (int i = 0; i < 4; ++i)
#pragma unroll
    for (int v = 0; v < 4; ++v) NV[i][v] = rowv[i * 16 + quad * 4 + v];
  __syncthreads();
#pragma unroll
  for (int i = 0; i < 4; ++i)
#pragma unroll
    for (int j = 0; j < 4; ++j)
#pragma unroll
      for (int v = 0; v < 4; ++v) acc[i][j][v] *= NV[i][v];

  // round 4: gate logit -> egate
  float GP[4][4];
#pragma unroll
  for (int i = 0; i < 4; ++i)
#pragma unroll
    for (int v = 0; v < 4; ++v) {
      float g = acc[i][0][v] * gw[0] + acc[i][1][v] * gw[1] +
                acc[i][2][v] * gw[2] + acc[i][3][v] * gw[3];
      GP[i][v] = red16_sum(g);
    }
  if (m16 == 0)
#pragma unroll
    for (int i = 0; i < 4; ++i)
#pragma unroll
      for (int v = 0; v < 4; ++v) red[wave][i * 16 + quad * 4 + v] = GP[i][v];
  __syncthreads();
  if (t < 64 && row0 + t < n_rows) {
    float gp = red[0][t] + red[1][t] + red[2][t] + red[3][t];
    egate[row0 + t] = __expf(gp + gate_b[0]);  // |gp| <= ~0.8, safe
  }
  // store y
#pragma unroll
  for (int i = 0; i < 4; ++i)
#pragma unroll
    for (int v = 0; v < 4; ++v) {
      int r = row0 + i * 16 + quad * 4 + v;
      if (r < n_rows) {
#pragma unroll
        for (int j = 0; j < 4; ++j)
          Cout[(size_t)r * 256 + wc + j * 16 + m16] = acc[i][j][v];
      }
    }
}

// ---- CSR build
__global__ void hist_kernel(const int* __restrict__ dst, int* __restrict__ deg, int e) {
  int i = blockIdx.x * 256 + threadIdx.x;
  if (i < e) atomicAdd(&deg[dst[i]], 1);
}

__global__ __launch_bounds__(1024) void scan_kernel(const int* __restrict__ deg,
                                                    int* __restrict__ offsets,
                                                    int* __restrict__ curs, int n) {
  __shared__ int wsum[16];
  __shared__ int carry_s;
  int t = threadIdx.x, lane = t & 63, wv = t >> 6;
  if (t == 0) { carry_s = 0; offsets[0] = 0; }
  __syncthreads();
  for (int base = 0; base < n; base += 4096) {
    int i0 = base + t * 4;
    int4 v = make_int4(0, 0, 0, 0);
    if (i0 + 3 < n) v = *(const int4*)(deg + i0);
    else {
      if (i0 < n) v.x = deg[i0];
      if (i0 + 1 < n) v.y = deg[i0 + 1];
      if (i0 + 2 < n) v.z = deg[i0 + 2];
    }
    int p1 = v.x, p2 = p1 + v.y, p3 = p2 + v.z, p4 = p3 + v.w;
    int s = p4;
#pragma unroll
    for (int d = 1; d < 64; d <<= 1) {
      int u = __shfl_up(s, d);
      if (lane >= d) s += u;
    }
    if (lane == 63) wsum[wv] = s;
    __syncthreads();
    int woff = 0, total = 0;
#pragma unroll
    for (int k = 0; k < 16; ++k) {
      int wsk = wsum[k];
      woff += (k < wv) ? wsk : 0;
      total += wsk;
    }
    int carry = carry_s;
    int excl = carry + woff + s - p4;
    if (i0 < n)     { offsets[i0 + 1] = excl + p1; curs[i0]     = excl; }
    if (i0 + 1 < n) { offsets[i0 + 2] = excl + p2; curs[i0 + 1] = excl + p1; }
    if (i0 + 2 < n) { offsets[i0 + 3] = excl + p3; curs[i0 + 2] = excl + p2; }
    if (i0 + 3 < n) { offsets[i0 + 4] = excl + p4; curs[i0 + 3] = excl + p3; }
    __syncthreads();
    if (t == 0) carry_s = carry + total;
    __syncthreads();
  }
}

// ---- simple scatter (pexp precompute reverted: agg is memory-path bound)
__global__ void scatter_kernel(const int* __restrict__ src, const int* __restrict__ dst,
                               int* __restrict__ cursor, int* __restrict__ ssrc, int e) {
  int i = blockIdx.x * 256 + threadIdx.x;
  if (i < e) {
    int p = atomicAdd(&cursor[dst[i]], 1);
    ssrc[p] = src[i];
  }
}

// ---- edge aggregation, bf16 gather, fp32 accumulate, unroll x8/x4/scalar.
__global__ __launch_bounds__(256) void agg_kernel(
    const unsigned short* __restrict__ xpb, const float* __restrict__ asrc,
    const float* __restrict__ adst, const int* __restrict__ offsets,
    const int* __restrict__ ssrc, const float4* __restrict__ conv_b4,
    float4* __restrict__ xloc4, int n_nodes) {
  int lane = threadIdx.x & 63, w = threadIdx.x >> 6;
  int n = blockIdx.x * 4 + w;
  if (n >= n_nodes) return;
  int h = lane >> 3;
  float ad = adst[n * 8 + h];
  float p = __expf(leaky_f(asrc[n * 8 + h] + ad, 0.2f));
  ushort4 xq = ((const ushort4*)(xpb + (size_t)n * 256))[lane];
  float4 acc;
  acc.x = p * bf2f(xq.x); acc.y = p * bf2f(xq.y);
  acc.z = p * bf2f(xq.z); acc.w = p * bf2f(xq.w);
  float ssum = p;
  int beg = offsets[n], end = offsets[n + 1];
  int j = beg;
  for (; j + 8 <= end; j += 8) {
    int sv[8];
#pragma unroll
    for (int u = 0; u < 8; ++u) sv[u] = ssrc[j + u];
    float a[8];
#pragma unroll
    for (int u = 0; u < 8; ++u) a[u] = asrc[sv[u] * 8 + h];
    ushort4 q[8];
#pragma unroll
    for (int u = 0; u < 8; ++u) q[u] = ((const ushort4*)(xpb + (size_t)sv[u] * 256))[lane];
#pragma unroll
    for (int u = 0; u < 8; ++u) {
      float pu = __expf(leaky_f(a[u] + ad, 0.2f));
      acc.x += pu * bf2f(q[u].x); acc.y += pu * bf2f(q[u].y);
      acc.z += pu * bf2f(q[u].z); acc.w += pu * bf2f(q[u].w);
      ssum += pu;
    }
  }
  for (; j + 4 <= end; j += 4) {
    int sv0 = ssrc[j], sv1 = ssrc[j + 1], sv2 = ssrc[j + 2], sv3 = ssrc[j + 3];
    float a0 = asrc[sv0 * 8 + h];
    float a1 = asrc[sv1 * 8 + h];
    float a2 = asrc[sv2 * 8 + h];
    float a3 = asrc[sv3 * 8 + h];
    ushort4 q0 = ((const ushort4*)(xpb + (size_t)sv0 * 256))[lane];
    ushort4 q1 = ((const ushort4*)(xpb + (size_t)sv1 * 256))[lane];
    ushort4 q2 = ((const ushort4*)(xpb + (size_t)sv2 * 256))[lane];
    ushort4 q3 = ((const ushort4*)(xpb + (size_t)sv3 * 256))[lane];
    float p0 = __expf(leaky_f(a0 + ad, 0.2f));
    float p1 = __expf(leaky_f(a1 + ad, 0.2f));
    float p2 = __expf(leaky_f(a2 + ad, 0.2f));
    float p3 = __expf(leaky_f(a3 + ad, 0.2f));
    acc.x += p0 * bf2f(q0.x); acc.y += p0 * bf2f(q0.y);
    acc.z += p0 * bf2f(q0.z); acc.w += p0 * bf2f(q0.w);
    acc.x += p1 * bf2f(q1.x); acc.y += p1 * bf2f(q1.y);
    acc.z += p1 * bf2f(q1.z); acc.w += p1 * bf2f(q1.w);
    acc.x += p2 * bf2f(q2.x); acc.y += p2 * bf2f(q2.y);
    acc.z += p2 * bf2f(q2.z); acc.w += p2 * bf2f(q2.w);
    acc.x += p3 * bf2f(q3.x); acc.y += p3 * bf2f(q3.y);
    acc.z += p3 * bf2f(q3.z); acc.w += p3 * bf2f(q3.w);
    ssum += p0 + p1 + p2 + p3;
  }
  for (; j < end; ++j) {
    int sv = ssrc[j];
    float a1 = asrc[sv * 8 + h];
    ushort4 q = ((const ushort4*)(xpb + (size_t)sv * 256))[lane];
    float p1 = __expf(leaky_f(a1 + ad, 0.2f));
    acc.x += p1 * bf2f(q.x); acc.y += p1 * bf2f(q.y);
    acc.z += p1 * bf2f(q.z); acc.w += p1 * bf2f(q.w);
    ssum += p1;
  }
  float inv = 1.f / (ssum + 1e-16f);
  float4 b = conv_b4[lane];
  float4 o;
  o.x = acc.x * inv + b.x; o.y = acc.y * inv + b.y;
  o.z = acc.z * inv + b.z; o.w = acc.w * inv + b.w;
  xloc4[(size_t)n * 64 + lane] = o;
}

// ---- pooling + Ssum: per-block partials, one atomic per block (512 blocks)
__global__ __launch_bounds__(256) void pool_kernel(const float* __restrict__ xloc,
                                                   const float* __restrict__ egate,
                                                   float* __restrict__ xg,
                                                   float* __restrict__ Ssum, int n) {
  int c = threadIdx.x;
  int rpb = (n + (int)gridDim.x - 1) / (int)gridDim.x;
  int r0 = blockIdx.x * rpb;
  int r1 = r0 + rpb; if (r1 > n) r1 = n;
  float acc = 0.f, gs = 0.f;
  for (int r = r0; r < r1; ++r) {
    float g = egate[r];
    acc += g * xloc[(size_t)r * 256 + c];
    gs += g;
  }
  atomicAdd(&xg[c], acc);
  if (c == 0) atomicAdd(Ssum, gs);
}

__global__ __launch_bounds__(256) void gfc_kernel(const float* __restrict__ xg,
                                                  const float* __restrict__ S,
                                                  const float* __restrict__ gfcT,
                                                  const float* __restrict__ gfc_b,
                                                  float* __restrict__ ga) {
  __shared__ float xs[256];
  __shared__ float red[256];
  int t = threadIdx.x;
  float invS = 1.f / (S[0] + 1e-16f);
  xs[t] = xg[t] * invS;
  __syncthreads();
  float acc = gfc_b[t];
  for (int i = 0; i < 256; ++i) acc += xs[i] * gfcT[i * 256 + t];
  acc = fmaxf(acc, 0.f);
  red[t] = acc;
  __syncthreads();
  for (int s = 128; s > 0; s >>= 1) {
    if (t < s) red[t] = fmaxf(red[t], red[t + s]);
    __syncthreads();
  }
  float m = red[0];
  __syncthreads();
  float e = __expf(acc - m);
  red[t] = e;
  __syncthreads();
  for (int s = 128; s > 0; s >>= 1) {
    if (t < s) red[t] += red[t + s];
    __syncthreads();
  }
  ga[t] = e / red[0];
}

__global__ void out_kernel(const float4* __restrict__ xloc4, const float4* __restrict__ ga4,
                           float4* __restrict__ out4, int total4) {
  int i = blockIdx.x * 256 + threadIdx.x;
  if (i >= total4) return;
  float4 v = xloc4[i];
  float4 g = ga4[i & 63];
  v.x *= g.x; v.y *= g.y; v.z *= g.z; v.w *= g.w;
  out4[i] = v;
}

extern "C" void kernel_launch(void* const* d_in, const int* in_sizes, int n_in,
                              void* d_out, int out_size, void* d_ws, size_t ws_size,
                              hipStream_t stream) {
  const float* x      = (const float*)d_in[0];
  const int* edge_idx = (const int*)d_in[1];
  const float* W      = (const float*)d_in[4];
  const float* a_src  = (const float*)d_in[5];
  const float* a_dst  = (const float*)d_in[6];
  const float* conv_b = (const float*)d_in[7];
  const float* fc_w   = (const float*)d_in[8];
  const float* fc_b   = (const float*)d_in[9];
  const float* ln_w   = (const float*)d_in[10];
  const float* ln_b   = (const float*)d_in[11];
  const float* gate_w = (const float*)d_in[12];
  const float* gate_b = (const float*)d_in[13];
  const float* gfc_w  = (const float*)d_in[14];
  const float* gfc_b  = (const float*)d_in[15];
  (void)n_in; (void)out_size; (void)ws_size;

  int N = in_sizes[0] / 128;
  int E = in_sizes[1] / 2;
  const int* src = edge_idx;
  const int* dst = edge_idx + E;

  char* p = (char*)d_ws;
  auto alloc = [&](size_t bytes) -> char* {
    char* r = p;
    p += (bytes + 255) & ~(size_t)255;
    return r;
  };
  float*          xloc = (float*)alloc((size_t)N * 256 * 4);          // conv out / final x
  unsigned short* xpb  = (unsigned short*)alloc((size_t)N * 256 * 2); // bf16 xp
  unsigned short* x2b  = (unsigned short*)alloc((size_t)N * 256 * 2); // bf16 x2
  float* asrc  = (float*)alloc((size_t)N * 8 * 4);
  float* adst  = (float*)alloc((size_t)N * 8 * 4);
  unsigned short* Wb   = (unsigned short*)alloc(256 * 128 * 2);
  unsigned short* fcB  = (unsigned short*)alloc(256 * 256 * 2);
  float* gfcT  = (float*)alloc(256 * 256 * 4);
  float* egate = (float*)alloc((size_t)N * 4);
  int*   deg   = (int*)alloc((size_t)N * 4);
  int*   offs  = (int*)alloc((size_t)(N + 1) * 4);
  int*   curs  = (int*)alloc((size_t)N * 4);
  int*   ssrc  = (int*)alloc((size_t)E * 4);
  float* Ssum  = (float*)alloc(256);
  float* xg    = (float*)alloc(1024);
  float* ga    = (float*)alloc(1024);

  int eb = (E + 255) / 256;
  int g64 = (N + 63) / 64;

  repack_zero_kernel<<<(256 * 128 + 2 * 256 * 256 + 255) / 256, 256, 0, stream>>>(
      W, fc_w, gfc_w, Wb, fcB, gfcT, deg, xg, Ssum, N);
  // xp(bf16) = x @ W, alpha fused
  gemm_xp<<<g64, 256, 0, stream>>>(x, Wb, a_src, a_dst, xpb, asrc, adst, N);
  hist_kernel<<<eb, 256, 0, stream>>>(dst, deg, E);
  scan_kernel<<<1, 1024, 0, stream>>>(deg, offs, curs, N);
  scatter_kernel<<<eb, 256, 0, stream>>>(src, dst, curs, ssrc, E);
  agg_kernel<<<(N + 3) / 4, 256, 0, stream>>>(
      xpb, asrc, adst, offs, ssrc, (const float4*)conv_b, (float4*)xloc, N);
  // fused: z1 -> softmax -> x2(bf16)
  gemm_sm<<<g64, 256, 0, stream>>>(xloc, fcB, fc_b, x2b, N);
  // fused: x3 -> LN -> L2 -> gate; writes xloc + egate
  gemm_ln<<<g64, 256, 0, stream>>>(x2b, fcB, fc_b, ln_w, ln_b, gate_w, gate_b,
                                   xloc, egate, N);
  pool_kernel<<<512, 256, 0, stream>>>(xloc, egate, xg, Ssum, N);
  gfc_kernel<<<1, 256, 0, stream>>>(xg, Ssum, gfcT, gfc_b, ga);
  out_kernel<<<(N * 64 + 255) / 256, 256, 0, stream>>>(
      (const float4*)xloc, (const float4*)ga, (float4*)d_out, N * 64);
}

// Round 9
// 321.529 us; speedup vs baseline: 1.2084x; 1.1182x over previous
//
#include <hip/hip_runtime.h>

// ---------------------------------------------------------------------------
// GAT pipeline. N=30000, E=600000, IN=128, H=8, HD=32, OUT=256.
// R1: removed per-node scalar atomic (925->549us).
// R2: bf16 MFMA GEMMs + bf16 gather (549->414us).
// R3/R4: agg software-pipelined x8; pool 512 blocks (->360us).
// R5/R6: GEMM+softmax, GEMM+LN fusion (->334us).
// R7 FAILED: 32-row/BK=32 tiles (388us: 8 MFMA/barrier, LDS conflicts).
// R8 FAILED: 64x256 + register prefetch (359us: prefetch VGPRs (~48 extra on
//     a 64-VGPR acc) cost a block/CU of occupancy — worse than no prefetch).
// R9: plain 64x256/BK=64 staging (the measured-good R6 body) + keep alpha
//     fusion, zero merge, simple scatter (11 dispatches).
// ---------------------------------------------------------------------------

typedef __attribute__((ext_vector_type(8))) short bf16x8;   // 8 bf16 (4 VGPRs)
typedef __attribute__((ext_vector_type(4))) float f32x4;    // MFMA acc

__device__ __forceinline__ float leaky_f(float v, float s) { return v > 0.f ? v : s * v; }
__device__ __forceinline__ unsigned short f2bf(float f) {   // RNE, no NaN expected
  unsigned int u = __float_as_uint(f);
  u += 0x7fffu + ((u >> 16) & 1u);
  return (unsigned short)(u >> 16);
}
__device__ __forceinline__ float bf2f(unsigned short u) {
  return __uint_as_float(((unsigned int)u) << 16);
}
__device__ __forceinline__ float red16_sum(float v) {
#pragma unroll
  for (int m = 1; m < 16; m <<= 1) v += __shfl_xor(v, m);
  return v;
}
__device__ __forceinline__ float red16_max(float v) {
#pragma unroll
  for (int m = 1; m < 16; m <<= 1) v = fmaxf(v, __shfl_xor(v, m));
  return v;
}

// ---- repack weights + zero accumulators (merged; independent jobs)
__global__ void repack_zero_kernel(const float* __restrict__ W, const float* __restrict__ fc_w,
                                   const float* __restrict__ gfc_w,
                                   unsigned short* __restrict__ Wb,
                                   unsigned short* __restrict__ fcB, float* __restrict__ gfcT,
                                   int* __restrict__ deg, float* __restrict__ xg,
                                   float* __restrict__ S, int n) {
  int i = blockIdx.x * 256 + threadIdx.x;
  if (i < 256 * 128) {
    int c = i >> 7, k = i & 127;
    Wb[i] = f2bf(W[((c >> 5) * 128 + k) * 32 + (c & 31)]);
  } else if (i < 256 * 128 + 256 * 256) {
    int j = i - 256 * 128;
    fcB[j] = f2bf(fc_w[j]);
  } else if (i < 256 * 128 + 2 * 256 * 256) {
    int j = i - 256 * 128 - 256 * 256;
    gfcT[j] = gfc_w[(j & 255) * 256 + (j >> 8)];
  }
  if (i < n) deg[i] = 0;
  if (i < 256) xg[i] = 0.f;
  if (i == 0) S[0] = 0.f;
}

// ---- shared 64x256 GEMM body (plain staging — the R6 measured-good body).
// Block = 64 rows x 256 cols, 4 waves (wave w -> cols w*64..w*64+63). BK=64.
// LDS stride 72 shorts = 144B -> 4-bank offset -> 2-way aliasing (free).
template <int A_BF16>
__device__ __forceinline__ void gemm_body_64x256(
    const void* __restrict__ Av, const unsigned short* __restrict__ B,
    int row0, int n_rows, int K, short As[64][72], short Bs[256][72],
    f32x4 acc[4][4]) {
  int t = threadIdx.x;
  int wave = t >> 6, lane = t & 63;
  int m16 = lane & 15, quad = lane >> 4;
  int wc = wave * 64;
  for (int k0 = 0; k0 < K; k0 += 64) {
    if (A_BF16) {
      const unsigned short* A = (const unsigned short*)Av;
#pragma unroll
      for (int p = 0; p < 2; ++p) {
        int e = (p * 256 + t) * 8;
        int row = e >> 6, k = e & 63;
        int ar = row0 + row; if (ar > n_rows - 1) ar = n_rows - 1;
        uint4 q = *(const uint4*)(A + (size_t)ar * K + k0 + k);
        *(uint4*)&As[row][k] = q;
      }
    } else {
      const float* A = (const float*)Av;
#pragma unroll
      for (int p = 0; p < 4; ++p) {
        int e = (p * 256 + t) * 4;
        int row = e >> 6, k = e & 63;
        int ar = row0 + row; if (ar > n_rows - 1) ar = n_rows - 1;
        float4 q = *(const float4*)(A + (size_t)ar * K + k0 + k);
        unsigned int lo = (unsigned int)f2bf(q.x) | ((unsigned int)f2bf(q.y) << 16);
        unsigned int hi = (unsigned int)f2bf(q.z) | ((unsigned int)f2bf(q.w) << 16);
        *(uint2*)&As[row][k] = make_uint2(lo, hi);
      }
    }
#pragma unroll
    for (int p = 0; p < 8; ++p) {
      int e = (p * 256 + t) * 8;
      int nn = e >> 6, k = e & 63;
      uint4 q = *(const uint4*)(B + (size_t)nn * K + k0 + k);
      *(uint4*)&Bs[nn][k] = q;
    }
    __syncthreads();
#pragma unroll
    for (int ks = 0; ks < 64; ks += 32) {
      bf16x8 af[4], bfr[4];
#pragma unroll
      for (int i = 0; i < 4; ++i)
        af[i] = *(const bf16x8*)&As[i * 16 + m16][ks + quad * 8];
#pragma unroll
      for (int j = 0; j < 4; ++j)
        bfr[j] = *(const bf16x8*)&Bs[wc + j * 16 + m16][ks + quad * 8];
#pragma unroll
      for (int i = 0; i < 4; ++i)
#pragma unroll
        for (int j = 0; j < 4; ++j)
          acc[i][j] = __builtin_amdgcn_mfma_f32_16x16x32_bf16(af[i], bfr[j], acc[i][j], 0, 0, 0);
    }
    __syncthreads();
  }
}

// ---- GEMM0 fused with alpha: xp = x@W (bf16 out); asrc/adst per-head dots
// from fp32 accumulators (wave w owns heads 2w, 2w+1: cols wc..wc+31, +32..63).
__global__ __launch_bounds__(256) void gemm_xp(
    const float* __restrict__ A, const unsigned short* __restrict__ B,
    const float* __restrict__ a_src, const float* __restrict__ a_dst,
    unsigned short* __restrict__ xpb, float* __restrict__ asrc,
    float* __restrict__ adst, int n_rows) {
  __shared__ short As[64][72];
  __shared__ short Bs[256][72];
  int t = threadIdx.x;
  int wave = t >> 6, lane = t & 63;
  int m16 = lane & 15, quad = lane >> 4;
  int wc = wave * 64;
  int row0 = blockIdx.x * 64;
  f32x4 acc[4][4];
#pragma unroll
  for (int i = 0; i < 4; ++i)
#pragma unroll
    for (int j = 0; j < 4; ++j) acc[i][j] = (f32x4){0.f, 0.f, 0.f, 0.f};
  gemm_body_64x256<0>(A, B, row0, n_rows, 128, As, Bs, acc);

  float av[4], bd[4];
#pragma unroll
  for (int j = 0; j < 4; ++j) {
    int c = wc + j * 16 + m16;
    av[j] = a_src[c];
    bd[j] = a_dst[c];
  }
#pragma unroll
  for (int i = 0; i < 4; ++i)
#pragma unroll
    for (int v = 0; v < 4; ++v) {
      int r = row0 + i * 16 + quad * 4 + v;
      if (r < n_rows) {
#pragma unroll
        for (int j = 0; j < 4; ++j)
          xpb[(size_t)r * 256 + wc + j * 16 + m16] = f2bf(acc[i][j][v]);
      }
      float s0 = acc[i][0][v] * av[0] + acc[i][1][v] * av[1];
      float s1 = acc[i][2][v] * av[2] + acc[i][3][v] * av[3];
      float d0 = acc[i][0][v] * bd[0] + acc[i][1][v] * bd[1];
      float d1 = acc[i][2][v] * bd[2] + acc[i][3][v] * bd[3];
      s0 = red16_sum(s0); s1 = red16_sum(s1);
      d0 = red16_sum(d0); d1 = red16_sum(d1);
      if (m16 == 0 && r < n_rows) {
        asrc[(size_t)r * 8 + 2 * wave] = s0;
        asrc[(size_t)r * 8 + 2 * wave + 1] = s1;
        adst[(size_t)r * 8 + 2 * wave] = d0;
        adst[(size_t)r * 8 + 2 * wave + 1] = d1;
      }
    }
}

// ---- GEMM1 fused with row softmax: z1 = leaky(xloc@fc^T+b, 0.01);
// sa = softmax(z1); x2b = bf16(leaky(xloc*sa, 0.2)).
__global__ __launch_bounds__(256) void gemm_sm(
    const float* __restrict__ A, const unsigned short* __restrict__ B,
    const float* __restrict__ bias, unsigned short* __restrict__ x2b, int n_rows) {
  __shared__ short As[64][72];
  __shared__ short Bs[256][72];
  __shared__ float red[4][64];
  __shared__ float rowv[64];
  int t = threadIdx.x;
  int wave = t >> 6, lane = t & 63;
  int m16 = lane & 15, quad = lane >> 4;
  int wc = wave * 64;
  int row0 = blockIdx.x * 64;
  f32x4 acc[4][4];
#pragma unroll
  for (int i = 0; i < 4; ++i)
#pragma unroll
    for (int j = 0; j < 4; ++j) acc[i][j] = (f32x4){0.f, 0.f, 0.f, 0.f};
  gemm_body_64x256<0>(A, B, row0, n_rows, 256, As, Bs, acc);

  float bvv[4];
#pragma unroll
  for (int j = 0; j < 4; ++j) bvv[j] = bias[wc + j * 16 + m16];
#pragma unroll
  for (int i = 0; i < 4; ++i)
#pragma unroll
    for (int j = 0; j < 4; ++j)
#pragma unroll
      for (int v = 0; v < 4; ++v)
        acc[i][j][v] = leaky_f(acc[i][j][v] + bvv[j], 0.01f);

  // row max
  float M[4][4];
#pragma unroll
  for (int i = 0; i < 4; ++i)
#pragma unroll
    for (int v = 0; v < 4; ++v) {
      float m = fmaxf(fmaxf(acc[i][0][v], acc[i][1][v]), fmaxf(acc[i][2][v], acc[i][3][v]));
      M[i][v] = red16_max(m);
    }
  if (m16 == 0)
#pragma unroll
    for (int i = 0; i < 4; ++i)
#pragma unroll
      for (int v = 0; v < 4; ++v) red[wave][i * 16 + quad * 4 + v] = M[i][v];
  __syncthreads();
  if (t < 64) rowv[t] = fmaxf(fmaxf(red[0][t], red[1][t]), fmaxf(red[2][t], red[3][t]));
  __syncthreads();
#pragma unroll
  for (int i = 0; i < 4; ++i)
#pragma unroll
    for (int v = 0; v < 4; ++v) M[i][v] = rowv[i * 16 + quad * 4 + v];
  __syncthreads();

  // exp + row sum
  float S[4][4];
#pragma unroll
  for (int i = 0; i < 4; ++i)
#pragma unroll
    for (int v = 0; v < 4; ++v) {
#pragma unroll
      for (int j = 0; j < 4; ++j) acc[i][j][v] = __expf(acc[i][j][v] - M[i][v]);
      float s = acc[i][0][v] + acc[i][1][v] + acc[i][2][v] + acc[i][3][v];
      S[i][v] = red16_sum(s);
    }
  if (m16 == 0)
#pragma unroll
    for (int i = 0; i < 4; ++i)
#pragma unroll
      for (int v = 0; v < 4; ++v) red[wave][i * 16 + quad * 4 + v] = S[i][v];
  __syncthreads();
  if (t < 64) rowv[t] = red[0][t] + red[1][t] + red[2][t] + red[3][t];
  __syncthreads();

  // x2 = leaky(xloc * e * inv, 0.2) -> bf16
#pragma unroll
  for (int i = 0; i < 4; ++i)
#pragma unroll
    for (int v = 0; v < 4; ++v) {
      int r = row0 + i * 16 + quad * 4 + v;
      float inv = 1.f / rowv[i * 16 + quad * 4 + v];
      if (r < n_rows) {
#pragma unroll
        for (int j = 0; j < 4; ++j) {
          int c = wc + j * 16 + m16;
          float xv = A[(size_t)r * 256 + c];
          x2b[(size_t)r * 256 + c] = f2bf(leaky_f(xv * acc[i][j][v] * inv, 0.2f));
        }
      }
    }
}

// ---- GEMM2 fused with LayerNorm + L2 norm + gate.
__global__ __launch_bounds__(256) void gemm_ln(
    const unsigned short* __restrict__ A, const unsigned short* __restrict__ B,
    const float* __restrict__ bias, const float* __restrict__ ln_w,
    const float* __restrict__ ln_b, const float* __restrict__ gate_w,
    const float* __restrict__ gate_b, float* __restrict__ Cout,
    float* __restrict__ egate, int n_rows) {
  __shared__ short As[64][72];
  __shared__ short Bs[256][72];
  __shared__ float red[4][64];
  __shared__ float rowv[64];
  int t = threadIdx.x;
  int wave = t >> 6, lane = t & 63;
  int m16 = lane & 15, quad = lane >> 4;
  int wc = wave * 64;
  int row0 = blockIdx.x * 64;
  f32x4 acc[4][4];
#pragma unroll
  for (int i = 0; i < 4; ++i)
#pragma unroll
    for (int j = 0; j < 4; ++j) acc[i][j] = (f32x4){0.f, 0.f, 0.f, 0.f};
  gemm_body_64x256<1>(A, B, row0, n_rows, 256, As, Bs, acc);

  float bvv[4], lw[4], lb[4], gw[4];
#pragma unroll
  for (int j = 0; j < 4; ++j) {
    int c = wc + j * 16 + m16;
    bvv[j] = bias[c]; lw[j] = ln_w[c]; lb[j] = ln_b[c]; gw[j] = gate_w[c];
  }
#pragma unroll
  for (int i = 0; i < 4; ++i)
#pragma unroll
    for (int j = 0; j < 4; ++j)
#pragma unroll
      for (int v = 0; v < 4; ++v) acc[i][j][v] += bvv[j];

  // round 1: mean
  float MU[4][4];
#pragma unroll
  for (int i = 0; i < 4; ++i)
#pragma unroll
    for (int v = 0; v < 4; ++v)
      MU[i][v] = red16_sum(acc[i][0][v] + acc[i][1][v] + acc[i][2][v] + acc[i][3][v]);
  if (m16 == 0)
#pragma unroll
    for (int i = 0; i < 4; ++i)
#pragma unroll
      for (int v = 0; v < 4; ++v) red[wave][i * 16 + quad * 4 + v] = MU[i][v];
  __syncthreads();
  if (t < 64) rowv[t] = (red[0][t] + red[1][t] + red[2][t] + red[3][t]) * (1.f / 256.f);
  __syncthreads();
#pragma unroll
  for (int i = 0; i < 4; ++i)
#pragma unroll
    for (int v = 0; v < 4; ++v) MU[i][v] = rowv[i * 16 + quad * 4 + v];
  __syncthreads();
#pragma unroll
  for (int i = 0; i < 4; ++i)
#pragma unroll
    for (int j = 0; j < 4; ++j)
#pragma unroll
      for (int v = 0; v < 4; ++v) acc[i][j][v] -= MU[i][v];

  // round 2: variance -> rstd
  float RS[4][4];
#pragma unroll
  for (int i = 0; i < 4; ++i)
#pragma unroll
    for (int v = 0; v < 4; ++v) {
      float q = acc[i][0][v] * acc[i][0][v] + acc[i][1][v] * acc[i][1][v] +
                acc[i][2][v] * acc[i][2][v] + acc[i][3][v] * acc[i][3][v];
      RS[i][v] = red16_sum(q);
    }
  if (m16 == 0)
#pragma unroll
    for (int i = 0; i < 4; ++i)
#pragma unroll
      for (int v = 0; v < 4; ++v) red[wave][i * 16 + quad * 4 + v] = RS[i][v];
  __syncthreads();
  if (t < 64)
    rowv[t] = rsqrtf((red[0][t] + red[1][t] + red[2][t] + red[3][t]) * (1.f / 256.f) + 1e-5f);
  __syncthreads();
#pragma unroll
  for (int i = 0; i < 4; ++i)
#pragma unroll
    for (int v = 0; v < 4; ++v) RS[i][v] = rowv[i * 16 + quad * 4 + v];
  __syncthreads();
#pragma unroll
  for (int i = 0; i < 4; ++i)
#pragma unroll
    for (int j = 0; j < 4; ++j)
#pragma unroll
      for (int v = 0; v < 4; ++v)
        acc[i][j][v] = acc[i][j][v] * RS[i][v] * lw[j] + lb[j];

  // round 3: L2 norm
  float NV[4][4];
#pragma unroll
  for (int i = 0; i < 4; ++i)
#pragma unroll
    for (int v = 0; v < 4; ++v) {
      float q = acc[i][0][v] * acc[i][0][v] + acc[i][1][v] * acc[i][1][v] +
                acc[i][2][v] * acc[i][2][v] + acc[i][3][v] * acc[i][3][v];
      NV[i][v] = red16_sum(q);
    }
  if (m16 == 0)
#pragma unroll
    for (int i = 0; i < 4; ++i)
#pragma unroll
      for (int v = 0; v < 4; ++v) red[wave][i * 16 + quad * 4 + v] = NV[i][v];
  __syncthreads();
  if (t < 64)
    rowv[t] = 1.f / fmaxf(sqrtf(red[0][t] + red[1][t] + red[2][t] + red[3][t]), 1e-12f);
  __syncthreads();
#pragma unroll
  for (int i = 0; i < 4; ++i)
#pragma unroll
    for (int v = 0; v < 4; ++v) NV[i][v] = rowv[i * 16 + quad * 4 + v];
  __syncthreads();
#pragma unroll
  for (int i = 0; i < 4; ++i)
#pragma unroll
    for (int j = 0; j < 4; ++j)
#pragma unroll
      for (int v = 0; v < 4; ++v) acc[i][j][v] *= NV[i][v];

  // round 4: gate logit -> egate
  float GP[4][4];
#pragma unroll
  for (int i = 0; i < 4; ++i)
#pragma unroll
    for (int v = 0; v < 4; ++v) {
      float g = acc[i][0][v] * gw[0] + acc[i][1][v] * gw[1] +
                acc[i][2][v] * gw[2] + acc[i][3][v] * gw[3];
      GP[i][v] = red16_sum(g);
    }
  if (m16 == 0)
#pragma unroll
    for (int i = 0; i < 4; ++i)
#pragma unroll
      for (int v = 0; v < 4; ++v) red[wave][i * 16 + quad * 4 + v] = GP[i][v];
  __syncthreads();
  if (t < 64 && row0 + t < n_rows) {
    float gp = red[0][t] + red[1][t] + red[2][t] + red[3][t];
    egate[row0 + t] = __expf(gp + gate_b[0]);  // |gp| <= ~0.8, safe
  }
  // store y
#pragma unroll
  for (int i = 0; i < 4; ++i)
#pragma unroll
    for (int v = 0; v < 4; ++v) {
      int r = row0 + i * 16 + quad * 4 + v;
      if (r < n_rows) {
#pragma unroll
        for (int j = 0; j < 4; ++j)
          Cout[(size_t)r * 256 + wc + j * 16 + m16] = acc[i][j][v];
      }
    }
}

// ---- CSR build
__global__ void hist_kernel(const int* __restrict__ dst, int* __restrict__ deg, int e) {
  int i = blockIdx.x * 256 + threadIdx.x;
  if (i < e) atomicAdd(&deg[dst[i]], 1);
}

__global__ __launch_bounds__(1024) void scan_kernel(const int* __restrict__ deg,
                                                    int* __restrict__ offsets,
                                                    int* __restrict__ curs, int n) {
  __shared__ int wsum[16];
  __shared__ int carry_s;
  int t = threadIdx.x, lane = t & 63, wv = t >> 6;
  if (t == 0) { carry_s = 0; offsets[0] = 0; }
  __syncthreads();
  for (int base = 0; base < n; base += 4096) {
    int i0 = base + t * 4;
    int4 v = make_int4(0, 0, 0, 0);
    if (i0 + 3 < n) v = *(const int4*)(deg + i0);
    else {
      if (i0 < n) v.x = deg[i0];
      if (i0 + 1 < n) v.y = deg[i0 + 1];
      if (i0 + 2 < n) v.z = deg[i0 + 2];
    }
    int p1 = v.x, p2 = p1 + v.y, p3 = p2 + v.z, p4 = p3 + v.w;
    int s = p4;
#pragma unroll
    for (int d = 1; d < 64; d <<= 1) {
      int u = __shfl_up(s, d);
      if (lane >= d) s += u;
    }
    if (lane == 63) wsum[wv] = s;
    __syncthreads();
    int woff = 0, total = 0;
#pragma unroll
    for (int k = 0; k < 16; ++k) {
      int wsk = wsum[k];
      woff += (k < wv) ? wsk : 0;
      total += wsk;
    }
    int carry = carry_s;
    int excl = carry + woff + s - p4;
    if (i0 < n)     { offsets[i0 + 1] = excl + p1; curs[i0]     = excl; }
    if (i0 + 1 < n) { offsets[i0 + 2] = excl + p2; curs[i0 + 1] = excl + p1; }
    if (i0 + 2 < n) { offsets[i0 + 3] = excl + p3; curs[i0 + 2] = excl + p2; }
    if (i0 + 3 < n) { offsets[i0 + 4] = excl + p4; curs[i0 + 3] = excl + p3; }
    __syncthreads();
    if (t == 0) carry_s = carry + total;
    __syncthreads();
  }
}

// ---- simple scatter
__global__ void scatter_kernel(const int* __restrict__ src, const int* __restrict__ dst,
                               int* __restrict__ cursor, int* __restrict__ ssrc, int e) {
  int i = blockIdx.x * 256 + threadIdx.x;
  if (i < e) {
    int p = atomicAdd(&cursor[dst[i]], 1);
    ssrc[p] = src[i];
  }
}

// ---- edge aggregation, bf16 gather, fp32 accumulate, unroll x8/x4/scalar.
__global__ __launch_bounds__(256) void agg_kernel(
    const unsigned short* __restrict__ xpb, const float* __restrict__ asrc,
    const float* __restrict__ adst, const int* __restrict__ offsets,
    const int* __restrict__ ssrc, const float4* __restrict__ conv_b4,
    float4* __restrict__ xloc4, int n_nodes) {
  int lane = threadIdx.x & 63, w = threadIdx.x >> 6;
  int n = blockIdx.x * 4 + w;
  if (n >= n_nodes) return;
  int h = lane >> 3;
  float ad = adst[n * 8 + h];
  float p = __expf(leaky_f(asrc[n * 8 + h] + ad, 0.2f));
  ushort4 xq = ((const ushort4*)(xpb + (size_t)n * 256))[lane];
  float4 acc;
  acc.x = p * bf2f(xq.x); acc.y = p * bf2f(xq.y);
  acc.z = p * bf2f(xq.z); acc.w = p * bf2f(xq.w);
  float ssum = p;
  int beg = offsets[n], end = offsets[n + 1];
  int j = beg;
  for (; j + 8 <= end; j += 8) {
    int sv[8];
#pragma unroll
    for (int u = 0; u < 8; ++u) sv[u] = ssrc[j + u];
    float a[8];
#pragma unroll
    for (int u = 0; u < 8; ++u) a[u] = asrc[sv[u] * 8 + h];
    ushort4 q[8];
#pragma unroll
    for (int u = 0; u < 8; ++u) q[u] = ((const ushort4*)(xpb + (size_t)sv[u] * 256))[lane];
#pragma unroll
    for (int u = 0; u < 8; ++u) {
      float pu = __expf(leaky_f(a[u] + ad, 0.2f));
      acc.x += pu * bf2f(q[u].x); acc.y += pu * bf2f(q[u].y);
      acc.z += pu * bf2f(q[u].z); acc.w += pu * bf2f(q[u].w);
      ssum += pu;
    }
  }
  for (; j + 4 <= end; j += 4) {
    int sv0 = ssrc[j], sv1 = ssrc[j + 1], sv2 = ssrc[j + 2], sv3 = ssrc[j + 3];
    float a0 = asrc[sv0 * 8 + h];
    float a1 = asrc[sv1 * 8 + h];
    float a2 = asrc[sv2 * 8 + h];
    float a3 = asrc[sv3 * 8 + h];
    ushort4 q0 = ((const ushort4*)(xpb + (size_t)sv0 * 256))[lane];
    ushort4 q1 = ((const ushort4*)(xpb + (size_t)sv1 * 256))[lane];
    ushort4 q2 = ((const ushort4*)(xpb + (size_t)sv2 * 256))[lane];
    ushort4 q3 = ((const ushort4*)(xpb + (size_t)sv3 * 256))[lane];
    float p0 = __expf(leaky_f(a0 + ad, 0.2f));
    float p1 = __expf(leaky_f(a1 + ad, 0.2f));
    float p2 = __expf(leaky_f(a2 + ad, 0.2f));
    float p3 = __expf(leaky_f(a3 + ad, 0.2f));
    acc.x += p0 * bf2f(q0.x); acc.y += p0 * bf2f(q0.y);
    acc.z += p0 * bf2f(q0.z); acc.w += p0 * bf2f(q0.w);
    acc.x += p1 * bf2f(q1.x); acc.y += p1 * bf2f(q1.y);
    acc.z += p1 * bf2f(q1.z); acc.w += p1 * bf2f(q1.w);
    acc.x += p2 * bf2f(q2.x); acc.y += p2 * bf2f(q2.y);
    acc.z += p2 * bf2f(q2.z); acc.w += p2 * bf2f(q2.w);
    acc.x += p3 * bf2f(q3.x); acc.y += p3 * bf2f(q3.y);
    acc.z += p3 * bf2f(q3.z); acc.w += p3 * bf2f(q3.w);
    ssum += p0 + p1 + p2 + p3;
  }
  for (; j < end; ++j) {
    int sv = ssrc[j];
    float a1 = asrc[sv * 8 + h];
    ushort4 q = ((const ushort4*)(xpb + (size_t)sv * 256))[lane];
    float p1 = __expf(leaky_f(a1 + ad, 0.2f));
    acc.x += p1 * bf2f(q.x); acc.y += p1 * bf2f(q.y);
    acc.z += p1 * bf2f(q.z); acc.w += p1 * bf2f(q.w);
    ssum += p1;
  }
  float inv = 1.f / (ssum + 1e-16f);
  float4 b = conv_b4[lane];
  float4 o;
  o.x = acc.x * inv + b.x; o.y = acc.y * inv + b.y;
  o.z = acc.z * inv + b.z; o.w = acc.w * inv + b.w;
  xloc4[(size_t)n * 64 + lane] = o;
}

// ---- pooling + Ssum: per-block partials, one atomic per block (512 blocks)
__global__ __launch_bounds__(256) void pool_kernel(const float* __restrict__ xloc,
                                                   const float* __restrict__ egate,
                                                   float* __restrict__ xg,
                                                   float* __restrict__ Ssum, int n) {
  int c = threadIdx.x;
  int rpb = (n + (int)gridDim.x - 1) / (int)gridDim.x;
  int r0 = blockIdx.x * rpb;
  int r1 = r0 + rpb; if (r1 > n) r1 = n;
  float acc = 0.f, gs = 0.f;
  for (int r = r0; r < r1; ++r) {
    float g = egate[r];
    acc += g * xloc[(size_t)r * 256 + c];
    gs += g;
  }
  atomicAdd(&xg[c], acc);
  if (c == 0) atomicAdd(Ssum, gs);
}

__global__ __launch_bounds__(256) void gfc_kernel(const float* __restrict__ xg,
                                                  const float* __restrict__ S,
                                                  const float* __restrict__ gfcT,
                                                  const float* __restrict__ gfc_b,
                                                  float* __restrict__ ga) {
  __shared__ float xs[256];
  __shared__ float red[256];
  int t = threadIdx.x;
  float invS = 1.f / (S[0] + 1e-16f);
  xs[t] = xg[t] * invS;
  __syncthreads();
  float acc = gfc_b[t];
  for (int i = 0; i < 256; ++i) acc += xs[i] * gfcT[i * 256 + t];
  acc = fmaxf(acc, 0.f);
  red[t] = acc;
  __syncthreads();
  for (int s = 128; s > 0; s >>= 1) {
    if (t < s) red[t] = fmaxf(red[t], red[t + s]);
    __syncthreads();
  }
  float m = red[0];
  __syncthreads();
  float e = __expf(acc - m);
  red[t] = e;
  __syncthreads();
  for (int s = 128; s > 0; s >>= 1) {
    if (t < s) red[t] += red[t + s];
    __syncthreads();
  }
  ga[t] = e / red[0];
}

__global__ void out_kernel(const float4* __restrict__ xloc4, const float4* __restrict__ ga4,
                           float4* __restrict__ out4, int total4) {
  int i = blockIdx.x * 256 + threadIdx.x;
  if (i >= total4) return;
  float4 v = xloc4[i];
  float4 g = ga4[i & 63];
  v.x *= g.x; v.y *= g.y; v.z *= g.z; v.w *= g.w;
  out4[i] = v;
}

extern "C" void kernel_launch(void* const* d_in, const int* in_sizes, int n_in,
                              void* d_out, int out_size, void* d_ws, size_t ws_size,
                              hipStream_t stream) {
  const float* x      = (const float*)d_in[0];
  const int* edge_idx = (const int*)d_in[1];
  const float* W      = (const float*)d_in[4];
  const float* a_src  = (const float*)d_in[5];
  const float* a_dst  = (const float*)d_in[6];
  const float* conv_b = (const float*)d_in[7];
  const float* fc_w   = (const float*)d_in[8];
  const float* fc_b   = (const float*)d_in[9];
  const float* ln_w   = (const float*)d_in[10];
  const float* ln_b   = (const float*)d_in[11];
  const float* gate_w = (const float*)d_in[12];
  const float* gate_b = (const float*)d_in[13];
  const float* gfc_w  = (const float*)d_in[14];
  const float* gfc_b  = (const float*)d_in[15];
  (void)n_in; (void)out_size; (void)ws_size;

  int N = in_sizes[0] / 128;
  int E = in_sizes[1] / 2;
  const int* src = edge_idx;
  const int* dst = edge_idx + E;

  char* p = (char*)d_ws;
  auto alloc = [&](size_t bytes) -> char* {
    char* r = p;
    p += (bytes + 255) & ~(size_t)255;
    return r;
  };
  float*          xloc = (float*)alloc((size_t)N * 256 * 4);          // conv out / final x
  unsigned short* xpb  = (unsigned short*)alloc((size_t)N * 256 * 2); // bf16 xp
  unsigned short* x2b  = (unsigned short*)alloc((size_t)N * 256 * 2); // bf16 x2
  float* asrc  = (float*)alloc((size_t)N * 8 * 4);
  float* adst  = (float*)alloc((size_t)N * 8 * 4);
  unsigned short* Wb   = (unsigned short*)alloc(256 * 128 * 2);
  unsigned short* fcB  = (unsigned short*)alloc(256 * 256 * 2);
  float* gfcT  = (float*)alloc(256 * 256 * 4);
  float* egate = (float*)alloc((size_t)N * 4);
  int*   deg   = (int*)alloc((size_t)N * 4);
  int*   offs  = (int*)alloc((size_t)(N + 1) * 4);
  int*   curs  = (int*)alloc((size_t)N * 4);
  int*   ssrc  = (int*)alloc((size_t)E * 4);
  float* Ssum  = (float*)alloc(256);
  float* xg    = (float*)alloc(1024);
  float* ga    = (float*)alloc(1024);

  int eb = (E + 255) / 256;
  int g64 = (N + 63) / 64;

  repack_zero_kernel<<<(256 * 128 + 2 * 256 * 256 + 255) / 256, 256, 0, stream>>>(
      W, fc_w, gfc_w, Wb, fcB, gfcT, deg, xg, Ssum, N);
  // xp(bf16) = x @ W, alpha fused
  gemm_xp<<<g64, 256, 0, stream>>>(x, Wb, a_src, a_dst, xpb, asrc, adst, N);
  hist_kernel<<<eb, 256, 0, stream>>>(dst, deg, E);
  scan_kernel<<<1, 1024, 0, stream>>>(deg, offs, curs, N);
  scatter_kernel<<<eb, 256, 0, stream>>>(src, dst, curs, ssrc, E);
  agg_kernel<<<(N + 3) / 4, 256, 0, stream>>>(
      xpb, asrc, adst, offs, ssrc, (const float4*)conv_b, (float4*)xloc, N);
  // fused: z1 -> softmax -> x2(bf16)
  gemm_sm<<<g64, 256, 0, stream>>>(xloc, fcB, fc_b, x2b, N);
  // fused: x3 -> LN -> L2 -> gate; writes xloc + egate
  gemm_ln<<<g64, 256, 0, stream>>>(x2b, fcB, fc_b, ln_w, ln_b, gate_w, gate_b,
                                   xloc, egate, N);
  pool_kernel<<<512, 256, 0, stream>>>(xloc, egate, xg, Ssum, N);
  gfc_kernel<<<1, 256, 0, stream>>>(xg, Ssum, gfcT, gfc_b, ga);
  out_kernel<<<(N * 64 + 255) / 256, 256, 0, stream>>>(
      (const float4*)xloc, (const float4*)ga, (float4*)d_out, N * 64);
}

// Round 10
// 301.918 us; speedup vs baseline: 1.2869x; 1.0650x over previous
//
#include <hip/hip_runtime.h>

// ---------------------------------------------------------------------------
// GAT pipeline. N=30000, E=600000, IN=128, H=8, HD=32, OUT=256.
// R1: removed per-node scalar atomic (925->549us).
// R2: bf16 MFMA GEMMs + bf16 gather (549->414us).
// R3/R4: agg software-pipelined x8; pool 512 blocks (->360us).
// R5/R6: GEMM+softmax, GEMM+LN fusion (->334us).
// R7 FAILED: 32-row/BK=32 tiles. R8 FAILED: register prefetch (VGPR cliff).
// R9: plain 64x256/BK=64 body + alpha fusion (->321us).
// R10: (a) hist+scan removed — padded-row CSR (ssrc[dst*96+p], count[]);
//      (b) scatter fused into gemm_xp as role-split grid (independent work);
//      (c) post-LN x stored bf16 (pool/out read bf16, -45MB);
//      (d) gfc folded into pool's last block (atomic ticket).
//      11 -> 7 dispatches.
// ---------------------------------------------------------------------------

#define PAD 96  // padded neighbor-list row; Poisson(20): P(deg>=96) < 1e-30

typedef __attribute__((ext_vector_type(8))) short bf16x8;   // 8 bf16 (4 VGPRs)
typedef __attribute__((ext_vector_type(4))) float f32x4;    // MFMA acc

__device__ __forceinline__ float leaky_f(float v, float s) { return v > 0.f ? v : s * v; }
__device__ __forceinline__ unsigned short f2bf(float f) {   // RNE, no NaN expected
  unsigned int u = __float_as_uint(f);
  u += 0x7fffu + ((u >> 16) & 1u);
  return (unsigned short)(u >> 16);
}
__device__ __forceinline__ float bf2f(unsigned short u) {
  return __uint_as_float(((unsigned int)u) << 16);
}
__device__ __forceinline__ float red16_sum(float v) {
#pragma unroll
  for (int m = 1; m < 16; m <<= 1) v += __shfl_xor(v, m);
  return v;
}
__device__ __forceinline__ float red16_max(float v) {
#pragma unroll
  for (int m = 1; m < 16; m <<= 1) v = fmaxf(v, __shfl_xor(v, m));
  return v;
}

// ---- repack weights + zero accumulators/counters (merged; independent jobs)
__global__ void repack_zero_kernel(const float* __restrict__ W, const float* __restrict__ fc_w,
                                   const float* __restrict__ gfc_w,
                                   unsigned short* __restrict__ Wb,
                                   unsigned short* __restrict__ fcB, float* __restrict__ gfcT,
                                   int* __restrict__ count, float* __restrict__ xg,
                                   float* __restrict__ S, int* __restrict__ done, int n) {
  int i = blockIdx.x * 256 + threadIdx.x;
  if (i < 256 * 128) {
    int c = i >> 7, k = i & 127;
    Wb[i] = f2bf(W[((c >> 5) * 128 + k) * 32 + (c & 31)]);
  } else if (i < 256 * 128 + 256 * 256) {
    int j = i - 256 * 128;
    fcB[j] = f2bf(fc_w[j]);
  } else if (i < 256 * 128 + 2 * 256 * 256) {
    int j = i - 256 * 128 - 256 * 256;
    gfcT[j] = gfc_w[(j & 255) * 256 + (j >> 8)];
  }
  if (i < n) count[i] = 0;
  if (i < 256) xg[i] = 0.f;
  if (i == 0) { S[0] = 0.f; done[0] = 0; }
}

// ---- shared 64x256 GEMM body (the R6/R9 measured-good body). 4 waves,
// wave w -> cols w*64..w*64+63, BK=64. LDS stride 72 shorts = free 2-way.
template <int A_BF16>
__device__ __forceinline__ void gemm_body_64x256(
    const void* __restrict__ Av, const unsigned short* __restrict__ B,
    int row0, int n_rows, int K, short As[64][72], short Bs[256][72],
    f32x4 acc[4][4]) {
  int t = threadIdx.x;
  int wave = t >> 6, lane = t & 63;
  int m16 = lane & 15, quad = lane >> 4;
  int wc = wave * 64;
  for (int k0 = 0; k0 < K; k0 += 64) {
    if (A_BF16) {
      const unsigned short* A = (const unsigned short*)Av;
#pragma unroll
      for (int p = 0; p < 2; ++p) {
        int e = (p * 256 + t) * 8;
        int row = e >> 6, k = e & 63;
        int ar = row0 + row; if (ar > n_rows - 1) ar = n_rows - 1;
        uint4 q = *(const uint4*)(A + (size_t)ar * K + k0 + k);
        *(uint4*)&As[row][k] = q;
      }
    } else {
      const float* A = (const float*)Av;
#pragma unroll
      for (int p = 0; p < 4; ++p) {
        int e = (p * 256 + t) * 4;
        int row = e >> 6, k = e & 63;
        int ar = row0 + row; if (ar > n_rows - 1) ar = n_rows - 1;
        float4 q = *(const float4*)(A + (size_t)ar * K + k0 + k);
        unsigned int lo = (unsigned int)f2bf(q.x) | ((unsigned int)f2bf(q.y) << 16);
        unsigned int hi = (unsigned int)f2bf(q.z) | ((unsigned int)f2bf(q.w) << 16);
        *(uint2*)&As[row][k] = make_uint2(lo, hi);
      }
    }
#pragma unroll
    for (int p = 0; p < 8; ++p) {
      int e = (p * 256 + t) * 8;
      int nn = e >> 6, k = e & 63;
      uint4 q = *(const uint4*)(B + (size_t)nn * K + k0 + k);
      *(uint4*)&Bs[nn][k] = q;
    }
    __syncthreads();
#pragma unroll
    for (int ks = 0; ks < 64; ks += 32) {
      bf16x8 af[4], bfr[4];
#pragma unroll
      for (int i = 0; i < 4; ++i)
        af[i] = *(const bf16x8*)&As[i * 16 + m16][ks + quad * 8];
#pragma unroll
      for (int j = 0; j < 4; ++j)
        bfr[j] = *(const bf16x8*)&Bs[wc + j * 16 + m16][ks + quad * 8];
#pragma unroll
      for (int i = 0; i < 4; ++i)
#pragma unroll
        for (int j = 0; j < 4; ++j)
          acc[i][j] = __builtin_amdgcn_mfma_f32_16x16x32_bf16(af[i], bfr[j], acc[i][j], 0, 0, 0);
    }
    __syncthreads();
  }
}

// ---- role-split kernel: blocks < gemm_blocks do (xp = x@W + alpha fusion);
// blocks >= gemm_blocks do the edge scatter (independent jobs, overlap).
__global__ __launch_bounds__(256) void gemm_xp_scatter(
    const float* __restrict__ A, const unsigned short* __restrict__ B,
    const float* __restrict__ a_src, const float* __restrict__ a_dst,
    unsigned short* __restrict__ xpb, float* __restrict__ asrc,
    float* __restrict__ adst, int n_rows,
    const int* __restrict__ esrc, const int* __restrict__ edst,
    int* __restrict__ count, int* __restrict__ ssrc, int E, int gemm_blocks) {
  __shared__ short As[64][72];
  __shared__ short Bs[256][72];
  if ((int)blockIdx.x >= gemm_blocks) {
    // ---- scatter role: padded-row CSR build
    int i = ((int)blockIdx.x - gemm_blocks) * 256 + threadIdx.x;
    if (i < E) {
      int d = edst[i];
      int p = atomicAdd(&count[d], 1);
      if (p < PAD) ssrc[(size_t)d * PAD + p] = esrc[i];
    }
    return;
  }
  // ---- GEMM role
  int t = threadIdx.x;
  int wave = t >> 6, lane = t & 63;
  int m16 = lane & 15, quad = lane >> 4;
  int wc = wave * 64;
  int row0 = blockIdx.x * 64;
  f32x4 acc[4][4];
#pragma unroll
  for (int i = 0; i < 4; ++i)
#pragma unroll
    for (int j = 0; j < 4; ++j) acc[i][j] = (f32x4){0.f, 0.f, 0.f, 0.f};
  gemm_body_64x256<0>(A, B, row0, n_rows, 128, As, Bs, acc);

  float av[4], bd[4];
#pragma unroll
  for (int j = 0; j < 4; ++j) {
    int c = wc + j * 16 + m16;
    av[j] = a_src[c];
    bd[j] = a_dst[c];
  }
#pragma unroll
  for (int i = 0; i < 4; ++i)
#pragma unroll
    for (int v = 0; v < 4; ++v) {
      int r = row0 + i * 16 + quad * 4 + v;
      if (r < n_rows) {
#pragma unroll
        for (int j = 0; j < 4; ++j)
          xpb[(size_t)r * 256 + wc + j * 16 + m16] = f2bf(acc[i][j][v]);
      }
      float s0 = acc[i][0][v] * av[0] + acc[i][1][v] * av[1];
      float s1 = acc[i][2][v] * av[2] + acc[i][3][v] * av[3];
      float d0 = acc[i][0][v] * bd[0] + acc[i][1][v] * bd[1];
      float d1 = acc[i][2][v] * bd[2] + acc[i][3][v] * bd[3];
      s0 = red16_sum(s0); s1 = red16_sum(s1);
      d0 = red16_sum(d0); d1 = red16_sum(d1);
      if (m16 == 0 && r < n_rows) {
        asrc[(size_t)r * 8 + 2 * wave] = s0;
        asrc[(size_t)r * 8 + 2 * wave + 1] = s1;
        adst[(size_t)r * 8 + 2 * wave] = d0;
        adst[(size_t)r * 8 + 2 * wave + 1] = d1;
      }
    }
}

// ---- GEMM1 fused with row softmax: z1 = leaky(xloc@fc^T+b, 0.01);
// sa = softmax(z1); x2b = bf16(leaky(xloc*sa, 0.2)).
__global__ __launch_bounds__(256) void gemm_sm(
    const float* __restrict__ A, const unsigned short* __restrict__ B,
    const float* __restrict__ bias, unsigned short* __restrict__ x2b, int n_rows) {
  __shared__ short As[64][72];
  __shared__ short Bs[256][72];
  __shared__ float red[4][64];
  __shared__ float rowv[64];
  int t = threadIdx.x;
  int wave = t >> 6, lane = t & 63;
  int m16 = lane & 15, quad = lane >> 4;
  int wc = wave * 64;
  int row0 = blockIdx.x * 64;
  f32x4 acc[4][4];
#pragma unroll
  for (int i = 0; i < 4; ++i)
#pragma unroll
    for (int j = 0; j < 4; ++j) acc[i][j] = (f32x4){0.f, 0.f, 0.f, 0.f};
  gemm_body_64x256<0>(A, B, row0, n_rows, 256, As, Bs, acc);

  float bvv[4];
#pragma unroll
  for (int j = 0; j < 4; ++j) bvv[j] = bias[wc + j * 16 + m16];
#pragma unroll
  for (int i = 0; i < 4; ++i)
#pragma unroll
    for (int j = 0; j < 4; ++j)
#pragma unroll
      for (int v = 0; v < 4; ++v)
        acc[i][j][v] = leaky_f(acc[i][j][v] + bvv[j], 0.01f);

  // row max
  float M[4][4];
#pragma unroll
  for (int i = 0; i < 4; ++i)
#pragma unroll
    for (int v = 0; v < 4; ++v) {
      float m = fmaxf(fmaxf(acc[i][0][v], acc[i][1][v]), fmaxf(acc[i][2][v], acc[i][3][v]));
      M[i][v] = red16_max(m);
    }
  if (m16 == 0)
#pragma unroll
    for (int i = 0; i < 4; ++i)
#pragma unroll
      for (int v = 0; v < 4; ++v) red[wave][i * 16 + quad * 4 + v] = M[i][v];
  __syncthreads();
  if (t < 64) rowv[t] = fmaxf(fmaxf(red[0][t], red[1][t]), fmaxf(red[2][t], red[3][t]));
  __syncthreads();
#pragma unroll
  for (int i = 0; i < 4; ++i)
#pragma unroll
    for (int v = 0; v < 4; ++v) M[i][v] = rowv[i * 16 + quad * 4 + v];
  __syncthreads();

  // exp + row sum
  float S[4][4];
#pragma unroll
  for (int i = 0; i < 4; ++i)
#pragma unroll
    for (int v = 0; v < 4; ++v) {
#pragma unroll
      for (int j = 0; j < 4; ++j) acc[i][j][v] = __expf(acc[i][j][v] - M[i][v]);
      float s = acc[i][0][v] + acc[i][1][v] + acc[i][2][v] + acc[i][3][v];
      S[i][v] = red16_sum(s);
    }
  if (m16 == 0)
#pragma unroll
    for (int i = 0; i < 4; ++i)
#pragma unroll
      for (int v = 0; v < 4; ++v) red[wave][i * 16 + quad * 4 + v] = S[i][v];
  __syncthreads();
  if (t < 64) rowv[t] = red[0][t] + red[1][t] + red[2][t] + red[3][t];
  __syncthreads();

  // x2 = leaky(xloc * e * inv, 0.2) -> bf16
#pragma unroll
  for (int i = 0; i < 4; ++i)
#pragma unroll
    for (int v = 0; v < 4; ++v) {
      int r = row0 + i * 16 + quad * 4 + v;
      float inv = 1.f / rowv[i * 16 + quad * 4 + v];
      if (r < n_rows) {
#pragma unroll
        for (int j = 0; j < 4; ++j) {
          int c = wc + j * 16 + m16;
          float xv = A[(size_t)r * 256 + c];
          x2b[(size_t)r * 256 + c] = f2bf(leaky_f(xv * acc[i][j][v] * inv, 0.2f));
        }
      }
    }
}

// ---- GEMM2 fused with LayerNorm + L2 norm + gate; output bf16.
__global__ __launch_bounds__(256) void gemm_ln(
    const unsigned short* __restrict__ A, const unsigned short* __restrict__ B,
    const float* __restrict__ bias, const float* __restrict__ ln_w,
    const float* __restrict__ ln_b, const float* __restrict__ gate_w,
    const float* __restrict__ gate_b, unsigned short* __restrict__ Cout,
    float* __restrict__ egate, int n_rows) {
  __shared__ short As[64][72];
  __shared__ short Bs[256][72];
  __shared__ float red[4][64];
  __shared__ float rowv[64];
  int t = threadIdx.x;
  int wave = t >> 6, lane = t & 63;
  int m16 = lane & 15, quad = lane >> 4;
  int wc = wave * 64;
  int row0 = blockIdx.x * 64;
  f32x4 acc[4][4];
#pragma unroll
  for (int i = 0; i < 4; ++i)
#pragma unroll
    for (int j = 0; j < 4; ++j) acc[i][j] = (f32x4){0.f, 0.f, 0.f, 0.f};
  gemm_body_64x256<1>(A, B, row0, n_rows, 256, As, Bs, acc);

  float bvv[4], lw[4], lb[4], gw[4];
#pragma unroll
  for (int j = 0; j < 4; ++j) {
    int c = wc + j * 16 + m16;
    bvv[j] = bias[c]; lw[j] = ln_w[c]; lb[j] = ln_b[c]; gw[j] = gate_w[c];
  }
#pragma unroll
  for (int i = 0; i < 4; ++i)
#pragma unroll
    for (int j = 0; j < 4; ++j)
#pragma unroll
      for (int v = 0; v < 4; ++v) acc[i][j][v] += bvv[j];

  // round 1: mean
  float MU[4][4];
#pragma unroll
  for (int i = 0; i < 4; ++i)
#pragma unroll
    for (int v = 0; v < 4; ++v)
      MU[i][v] = red16_sum(acc[i][0][v] + acc[i][1][v] + acc[i][2][v] + acc[i][3][v]);
  if (m16 == 0)
#pragma unroll
    for (int i = 0; i < 4; ++i)
#pragma unroll
      for (int v = 0; v < 4; ++v) red[wave][i * 16 + quad * 4 + v] = MU[i][v];
  __syncthreads();
  if (t < 64) rowv[t] = (red[0][t] + red[1][t] + red[2][t] + red[3][t]) * (1.f / 256.f);
  __syncthreads();
#pragma unroll
  for (int i = 0; i < 4; ++i)
#pragma unroll
    for (int v = 0; v < 4; ++v) MU[i][v] = rowv[i * 16 + quad * 4 + v];
  __syncthreads();
#pragma unroll
  for (int i = 0; i < 4; ++i)
#pragma unroll
    for (int j = 0; j < 4; ++j)
#pragma unroll
      for (int v = 0; v < 4; ++v) acc[i][j][v] -= MU[i][v];

  // round 2: variance -> rstd
  float RS[4][4];
#pragma unroll
  for (int i = 0; i < 4; ++i)
#pragma unroll
    for (int v = 0; v < 4; ++v) {
      float q = acc[i][0][v] * acc[i][0][v] + acc[i][1][v] * acc[i][1][v] +
                acc[i][2][v] * acc[i][2][v] + acc[i][3][v] * acc[i][3][v];
      RS[i][v] = red16_sum(q);
    }
  if (m16 == 0)
#pragma unroll
    for (int i = 0; i < 4; ++i)
#pragma unroll
      for (int v = 0; v < 4; ++v) red[wave][i * 16 + quad * 4 + v] = RS[i][v];
  __syncthreads();
  if (t < 64)
    rowv[t] = rsqrtf((red[0][t] + red[1][t] + red[2][t] + red[3][t]) * (1.f / 256.f) + 1e-5f);
  __syncthreads();
#pragma unroll
  for (int i = 0; i < 4; ++i)
#pragma unroll
    for (int v = 0; v < 4; ++v) RS[i][v] = rowv[i * 16 + quad * 4 + v];
  __syncthreads();
#pragma unroll
  for (int i = 0; i < 4; ++i)
#pragma unroll
    for (int j = 0; j < 4; ++j)
#pragma unroll
      for (int v = 0; v < 4; ++v)
        acc[i][j][v] = acc[i][j][v] * RS[i][v] * lw[j] + lb[j];

  // round 3: L2 norm
  float NV[4][4];
#pragma unroll
  for (int i = 0; i < 4; ++i)
#pragma unroll
    for (int v = 0; v < 4; ++v) {
      float q = acc[i][0][v] * acc[i][0][v] + acc[i][1][v] * acc[i][1][v] +
                acc[i][2][v] * acc[i][2][v] + acc[i][3][v] * acc[i][3][v];
      NV[i][v] = red16_sum(q);
    }
  if (m16 == 0)
#pragma unroll
    for (int i = 0; i < 4; ++i)
#pragma unroll
      for (int v = 0; v < 4; ++v) red[wave][i * 16 + quad * 4 + v] = NV[i][v];
  __syncthreads();
  if (t < 64)
    rowv[t] = 1.f / fmaxf(sqrtf(red[0][t] + red[1][t] + red[2][t] + red[3][t]), 1e-12f);
  __syncthreads();
#pragma unroll
  for (int i = 0; i < 4; ++i)
#pragma unroll
    for (int v = 0; v < 4; ++v) NV[i][v] = rowv[i * 16 + quad * 4 + v];
  __syncthreads();
#pragma unroll
  for (int i = 0; i < 4; ++i)
#pragma unroll
    for (int j = 0; j < 4; ++j)
#pragma unroll
      for (int v = 0; v < 4; ++v) acc[i][j][v] *= NV[i][v];

  // round 4: gate logit -> egate
  float GP[4][4];
#pragma unroll
  for (int i = 0; i < 4; ++i)
#pragma unroll
    for (int v = 0; v < 4; ++v) {
      float g = acc[i][0][v] * gw[0] + acc[i][1][v] * gw[1] +
                acc[i][2][v] * gw[2] + acc[i][3][v] * gw[3];
      GP[i][v] = red16_sum(g);
    }
  if (m16 == 0)
#pragma unroll
    for (int i = 0; i < 4; ++i)
#pragma unroll
      for (int v = 0; v < 4; ++v) red[wave][i * 16 + quad * 4 + v] = GP[i][v];
  __syncthreads();
  if (t < 64 && row0 + t < n_rows) {
    float gp = red[0][t] + red[1][t] + red[2][t] + red[3][t];
    egate[row0 + t] = __expf(gp + gate_b[0]);  // |gp| <= ~0.8, safe
  }
  // store y (bf16)
#pragma unroll
  for (int i = 0; i < 4; ++i)
#pragma unroll
    for (int v = 0; v < 4; ++v) {
      int r = row0 + i * 16 + quad * 4 + v;
      if (r < n_rows) {
#pragma unroll
        for (int j = 0; j < 4; ++j)
          Cout[(size_t)r * 256 + wc + j * 16 + m16] = f2bf(acc[i][j][v]);
      }
    }
}

// ---- edge aggregation: padded-row CSR, bf16 gather, unroll x8/x4/scalar.
__global__ __launch_bounds__(256) void agg_kernel(
    const unsigned short* __restrict__ xpb, const float* __restrict__ asrc,
    const float* __restrict__ adst, const int* __restrict__ count,
    const int* __restrict__ ssrc, const float4* __restrict__ conv_b4,
    float4* __restrict__ xloc4, int n_nodes) {
  int lane = threadIdx.x & 63, w = threadIdx.x >> 6;
  int n = blockIdx.x * 4 + w;
  if (n >= n_nodes) return;
  int h = lane >> 3;
  float ad = adst[n * 8 + h];
  float p = __expf(leaky_f(asrc[n * 8 + h] + ad, 0.2f));
  ushort4 xq = ((const ushort4*)(xpb + (size_t)n * 256))[lane];
  float4 acc;
  acc.x = p * bf2f(xq.x); acc.y = p * bf2f(xq.y);
  acc.z = p * bf2f(xq.z); acc.w = p * bf2f(xq.w);
  float ssum = p;
  int beg = n * PAD;
  int end = beg + count[n];
  int j = beg;
  for (; j + 8 <= end; j += 8) {
    int sv[8];
#pragma unroll
    for (int u = 0; u < 8; ++u) sv[u] = ssrc[j + u];
    float a[8];
#pragma unroll
    for (int u = 0; u < 8; ++u) a[u] = asrc[sv[u] * 8 + h];
    ushort4 q[8];
#pragma unroll
    for (int u = 0; u < 8; ++u) q[u] = ((const ushort4*)(xpb + (size_t)sv[u] * 256))[lane];
#pragma unroll
    for (int u = 0; u < 8; ++u) {
      float pu = __expf(leaky_f(a[u] + ad, 0.2f));
      acc.x += pu * bf2f(q[u].x); acc.y += pu * bf2f(q[u].y);
      acc.z += pu * bf2f(q[u].z); acc.w += pu * bf2f(q[u].w);
      ssum += pu;
    }
  }
  for (; j + 4 <= end; j += 4) {
    int sv0 = ssrc[j], sv1 = ssrc[j + 1], sv2 = ssrc[j + 2], sv3 = ssrc[j + 3];
    float a0 = asrc[sv0 * 8 + h];
    float a1 = asrc[sv1 * 8 + h];
    float a2 = asrc[sv2 * 8 + h];
    float a3 = asrc[sv3 * 8 + h];
    ushort4 q0 = ((const ushort4*)(xpb + (size_t)sv0 * 256))[lane];
    ushort4 q1 = ((const ushort4*)(xpb + (size_t)sv1 * 256))[lane];
    ushort4 q2 = ((const ushort4*)(xpb + (size_t)sv2 * 256))[lane];
    ushort4 q3 = ((const ushort4*)(xpb + (size_t)sv3 * 256))[lane];
    float p0 = __expf(leaky_f(a0 + ad, 0.2f));
    float p1 = __expf(leaky_f(a1 + ad, 0.2f));
    float p2 = __expf(leaky_f(a2 + ad, 0.2f));
    float p3 = __expf(leaky_f(a3 + ad, 0.2f));
    acc.x += p0 * bf2f(q0.x); acc.y += p0 * bf2f(q0.y);
    acc.z += p0 * bf2f(q0.z); acc.w += p0 * bf2f(q0.w);
    acc.x += p1 * bf2f(q1.x); acc.y += p1 * bf2f(q1.y);
    acc.z += p1 * bf2f(q1.z); acc.w += p1 * bf2f(q1.w);
    acc.x += p2 * bf2f(q2.x); acc.y += p2 * bf2f(q2.y);
    acc.z += p2 * bf2f(q2.z); acc.w += p2 * bf2f(q2.w);
    acc.x += p3 * bf2f(q3.x); acc.y += p3 * bf2f(q3.y);
    acc.z += p3 * bf2f(q3.z); acc.w += p3 * bf2f(q3.w);
    ssum += p0 + p1 + p2 + p3;
  }
  for (; j < end; ++j) {
    int sv = ssrc[j];
    float a1 = asrc[sv * 8 + h];
    ushort4 q = ((const ushort4*)(xpb + (size_t)sv * 256))[lane];
    float p1 = __expf(leaky_f(a1 + ad, 0.2f));
    acc.x += p1 * bf2f(q.x); acc.y += p1 * bf2f(q.y);
    acc.z += p1 * bf2f(q.z); acc.w += p1 * bf2f(q.w);
    ssum += p1;
  }
  float inv = 1.f / (ssum + 1e-16f);
  float4 b = conv_b4[lane];
  float4 o;
  o.x = acc.x * inv + b.x; o.y = acc.y * inv + b.y;
  o.z = acc.z * inv + b.z; o.w = acc.w * inv + b.w;
  xloc4[(size_t)n * 64 + lane] = o;
}

// ---- pooling + Ssum + (last block) gfc softmax. bf16 x input.
__global__ __launch_bounds__(256) void pool_gfc(
    const unsigned short* __restrict__ xlb, const float* __restrict__ egate,
    float* __restrict__ xg, float* __restrict__ Ssum, int n, int* __restrict__ done,
    const float* __restrict__ gfcT, const float* __restrict__ gfc_b,
    float* __restrict__ ga) {
  int c = threadIdx.x;
  int rpb = (n + (int)gridDim.x - 1) / (int)gridDim.x;
  int r0 = blockIdx.x * rpb;
  int r1 = r0 + rpb; if (r1 > n) r1 = n;
  float acc = 0.f, gs = 0.f;
  for (int r = r0; r < r1; ++r) {
    float g = egate[r];
    acc += g * bf2f(xlb[(size_t)r * 256 + c]);
    gs += g;
  }
  atomicAdd(&xg[c], acc);
  if (c == 0) atomicAdd(Ssum, gs);
  __threadfence();
  __shared__ int isLast;
  if (c == 0) {
    int ticket = atomicAdd(done, 1);
    isLast = (ticket == (int)gridDim.x - 1);
  }
  __syncthreads();
  if (!isLast) return;
  // ---- gfc phase (single surviving block). Coherent reads via atomicAdd 0.
  __shared__ float xs[256];
  __shared__ float red[256];
  __shared__ float Sv;
  if (c == 0) Sv = atomicAdd(Ssum, 0.f);
  float xgc = atomicAdd(&xg[c], 0.f);
  __syncthreads();
  xs[c] = xgc / (Sv + 1e-16f);
  __syncthreads();
  float a = gfc_b[c];
  for (int i = 0; i < 256; ++i) a += xs[i] * gfcT[i * 256 + c];
  a = fmaxf(a, 0.f);
  red[c] = a;
  __syncthreads();
  for (int s = 128; s > 0; s >>= 1) {
    if (c < s) red[c] = fmaxf(red[c], red[c + s]);
    __syncthreads();
  }
  float m = red[0];
  __syncthreads();
  float e = __expf(a - m);
  red[c] = e;
  __syncthreads();
  for (int s = 128; s > 0; s >>= 1) {
    if (c < s) red[c] += red[c + s];
    __syncthreads();
  }
  ga[c] = e / red[0];
}

// ---- out[n,c] = bf2f(x[n,c]) * ga[c]
__global__ void out_kernel(const ushort4* __restrict__ xlb4, const float4* __restrict__ ga4,
                           float4* __restrict__ out4, int total4) {
  int i = blockIdx.x * 256 + threadIdx.x;
  if (i >= total4) return;
  ushort4 q = xlb4[i];
  float4 g = ga4[i & 63];
  float4 v;
  v.x = bf2f(q.x) * g.x; v.y = bf2f(q.y) * g.y;
  v.z = bf2f(q.z) * g.z; v.w = bf2f(q.w) * g.w;
  out4[i] = v;
}

extern "C" void kernel_launch(void* const* d_in, const int* in_sizes, int n_in,
                              void* d_out, int out_size, void* d_ws, size_t ws_size,
                              hipStream_t stream) {
  const float* x      = (const float*)d_in[0];
  const int* edge_idx = (const int*)d_in[1];
  const float* W      = (const float*)d_in[4];
  const float* a_src  = (const float*)d_in[5];
  const float* a_dst  = (const float*)d_in[6];
  const float* conv_b = (const float*)d_in[7];
  const float* fc_w   = (const float*)d_in[8];
  const float* fc_b   = (const float*)d_in[9];
  const float* ln_w   = (const float*)d_in[10];
  const float* ln_b   = (const float*)d_in[11];
  const float* gate_w = (const float*)d_in[12];
  const float* gate_b = (const float*)d_in[13];
  const float* gfc_w  = (const float*)d_in[14];
  const float* gfc_b  = (const float*)d_in[15];
  (void)n_in; (void)out_size; (void)ws_size;

  int N = in_sizes[0] / 128;
  int E = in_sizes[1] / 2;
  const int* src = edge_idx;
  const int* dst = edge_idx + E;

  char* p = (char*)d_ws;
  auto alloc = [&](size_t bytes) -> char* {
    char* r = p;
    p += (bytes + 255) & ~(size_t)255;
    return r;
  };
  float*          xloc = (float*)alloc((size_t)N * 256 * 4);          // agg out (fp32)
  unsigned short* xpb  = (unsigned short*)alloc((size_t)N * 256 * 2); // bf16 xp
  unsigned short* x2b  = (unsigned short*)alloc((size_t)N * 256 * 2); // bf16 x2
  unsigned short* xlb  = (unsigned short*)alloc((size_t)N * 256 * 2); // bf16 post-LN x
  float* asrc  = (float*)alloc((size_t)N * 8 * 4);
  float* adst  = (float*)alloc((size_t)N * 8 * 4);
  unsigned short* Wb   = (unsigned short*)alloc(256 * 128 * 2);
  unsigned short* fcB  = (unsigned short*)alloc(256 * 256 * 2);
  float* gfcT  = (float*)alloc(256 * 256 * 4);
  float* egate = (float*)alloc((size_t)N * 4);
  int*   count = (int*)alloc((size_t)N * 4);
  int*   ssrc  = (int*)alloc((size_t)N * PAD * 4);
  float* Ssum  = (float*)alloc(256);
  int*   done  = (int*)alloc(256);
  float* xg    = (float*)alloc(1024);
  float* ga    = (float*)alloc(1024);

  int eb = (E + 255) / 256;
  int g64 = (N + 63) / 64;

  repack_zero_kernel<<<(256 * 128 + 2 * 256 * 256 + 255) / 256, 256, 0, stream>>>(
      W, fc_w, gfc_w, Wb, fcB, gfcT, count, xg, Ssum, done, N);
  // role-split: GEMM0 (xp + alpha) blocks 0..g64-1 | scatter blocks g64..
  gemm_xp_scatter<<<g64 + eb, 256, 0, stream>>>(
      x, Wb, a_src, a_dst, xpb, asrc, adst, N, src, dst, count, ssrc, E, g64);
  agg_kernel<<<(N + 3) / 4, 256, 0, stream>>>(
      xpb, asrc, adst, count, ssrc, (const float4*)conv_b, (float4*)xloc, N);
  // fused: z1 -> softmax -> x2(bf16)
  gemm_sm<<<g64, 256, 0, stream>>>(xloc, fcB, fc_b, x2b, N);
  // fused: x3 -> LN -> L2 -> gate; writes xlb(bf16) + egate
  gemm_ln<<<g64, 256, 0, stream>>>(x2b, fcB, fc_b, ln_w, ln_b, gate_w, gate_b,
                                   xlb, egate, N);
  // pooling + last-block gfc softmax
  pool_gfc<<<512, 256, 0, stream>>>(xlb, egate, xg, Ssum, N, done, gfcT, gfc_b, ga);
  out_kernel<<<(N * 64 + 255) / 256, 256, 0, stream>>>(
      (const ushort4*)xlb, (const float4*)ga, (float4*)d_out, N * 64);
}